// Round 1
// baseline (2834.611 us; speedup 1.0000x reference)
//
#include <hip/hip_runtime.h>
#include <math.h>

#define NROWS 200000
#define DIM   512
#define KC    256
#define NCHUNKS 100
#define NCHUNK  2000   // rows per mean chunk (100*2000 = 200000)

// ---------------- transpose: src[R][C] -> dst[C][R] ----------------
__global__ __launch_bounds__(256) void transpose_kernel(const float* __restrict__ src,
                                                        float* __restrict__ dst,
                                                        int R, int C) {
  __shared__ float tile[32][33];
  const int tx = threadIdx.x;           // 0..31
  const int ty = threadIdx.y;           // 0..7
  const int c0 = blockIdx.x * 32;
  const int r0 = blockIdx.y * 32;
#pragma unroll
  for (int j = 0; j < 32; j += 8)
    tile[ty + j][tx] = src[(size_t)(r0 + ty + j) * C + c0 + tx];
  __syncthreads();
#pragma unroll
  for (int j = 0; j < 32; j += 8)
    dst[(size_t)(c0 + ty + j) * R + r0 + tx] = tile[tx][ty + j];
}

// ---------------- fused MLP (3 layers) + softmax + argmax ----------------
// Block: 256 threads, 32 rows, full K=256 columns.
// Thread (cg = t&31, rg = t>>5): rows rg*4+i (i<4), cols cg*4 + 128*j + c (j<2, c<4).
__global__ __launch_bounds__(256, 2) void mlp_softmax_kernel(
    const float* __restrict__ E,
    const float* __restrict__ W1T, const float* __restrict__ W2T,
    const float* __restrict__ W3T,
    const float* __restrict__ b1, const float* __restrict__ b2,
    const float* __restrict__ b3,
    float* __restrict__ gamma, float* __restrict__ idx_out,
    float* __restrict__ gsp) {
  __shared__ float Xa[32][KC];
  __shared__ float Xb[32][KC];
  __shared__ float Wt[8][KC];
  __shared__ float Et[8][32];
  __shared__ float gs[KC];

  const int t = threadIdx.x;
  const int blk = blockIdx.x;
  const size_t rbase = (size_t)blk * 32;
  const int cg = t & 31;
  const int rg = t >> 5;

  gs[t] = 0.0f;

  float acc[4][2][4];

  // ===================== layer 1: Xa = leaky(E @ W1^T + b1) =====================
#pragma unroll
  for (int i = 0; i < 4; ++i)
#pragma unroll
    for (int j = 0; j < 2; ++j)
#pragma unroll
      for (int c = 0; c < 4; ++c) acc[i][j][c] = 0.0f;

  for (int d0 = 0; d0 < DIM; d0 += 8) {
    // stage W tile [8 d][256 k] (coalesced from pre-transposed W1T)
    const float4* wsrc = (const float4*)(W1T + (size_t)d0 * KC);
    float4* wdst = (float4*)(&Wt[0][0]);
    wdst[t] = wsrc[t];
    wdst[t + 256] = wsrc[t + 256];
    // stage E tile transposed [8 d][32 rows]
    Et[t & 7][t >> 3] = E[(rbase + (size_t)(t >> 3)) * DIM + d0 + (t & 7)];
    __syncthreads();
#pragma unroll
    for (int dd = 0; dd < 8; ++dd) {
      float4 e4 = *(const float4*)(&Et[dd][rg * 4]);
      float4 w0 = *(const float4*)(&Wt[dd][cg * 4]);
      float4 w1 = *(const float4*)(&Wt[dd][cg * 4 + 128]);
      float ev[4] = {e4.x, e4.y, e4.z, e4.w};
      float wv[2][4] = {{w0.x, w0.y, w0.z, w0.w}, {w1.x, w1.y, w1.z, w1.w}};
#pragma unroll
      for (int i = 0; i < 4; ++i)
#pragma unroll
        for (int j = 0; j < 2; ++j)
#pragma unroll
          for (int c = 0; c < 4; ++c)
            acc[i][j][c] = fmaf(ev[i], wv[j][c], acc[i][j][c]);
    }
    __syncthreads();
  }
  {
    float4 bb0 = *(const float4*)(b1 + cg * 4);
    float4 bb1 = *(const float4*)(b1 + cg * 4 + 128);
    float bv[2][4] = {{bb0.x, bb0.y, bb0.z, bb0.w}, {bb1.x, bb1.y, bb1.z, bb1.w}};
#pragma unroll
    for (int i = 0; i < 4; ++i)
#pragma unroll
      for (int j = 0; j < 2; ++j) {
        float4 v;
        float vv[4];
#pragma unroll
        for (int c = 0; c < 4; ++c) {
          float x = acc[i][j][c] + bv[j][c];
          vv[c] = x > 0.0f ? x : 0.01f * x;
        }
        v.x = vv[0]; v.y = vv[1]; v.z = vv[2]; v.w = vv[3];
        *(float4*)(&Xa[rg * 4 + i][cg * 4 + j * 128]) = v;
      }
  }
  __syncthreads();

  // ===================== layer 2: Xb = leaky(Xa @ W2^T + b2) =====================
#pragma unroll
  for (int i = 0; i < 4; ++i)
#pragma unroll
    for (int j = 0; j < 2; ++j)
#pragma unroll
      for (int c = 0; c < 4; ++c) acc[i][j][c] = 0.0f;

  for (int d0 = 0; d0 < KC; d0 += 8) {
    const float4* wsrc = (const float4*)(W2T + (size_t)d0 * KC);
    float4* wdst = (float4*)(&Wt[0][0]);
    wdst[t] = wsrc[t];
    wdst[t + 256] = wsrc[t + 256];
    __syncthreads();
#pragma unroll
    for (int dd = 0; dd < 8; ++dd) {
      const int d = d0 + dd;
      float ev[4];
#pragma unroll
      for (int i = 0; i < 4; ++i) ev[i] = Xa[rg * 4 + i][d];
      float4 w0 = *(const float4*)(&Wt[dd][cg * 4]);
      float4 w1 = *(const float4*)(&Wt[dd][cg * 4 + 128]);
      float wv[2][4] = {{w0.x, w0.y, w0.z, w0.w}, {w1.x, w1.y, w1.z, w1.w}};
#pragma unroll
      for (int i = 0; i < 4; ++i)
#pragma unroll
        for (int j = 0; j < 2; ++j)
#pragma unroll
          for (int c = 0; c < 4; ++c)
            acc[i][j][c] = fmaf(ev[i], wv[j][c], acc[i][j][c]);
    }
    __syncthreads();
  }
  {
    float4 bb0 = *(const float4*)(b2 + cg * 4);
    float4 bb1 = *(const float4*)(b2 + cg * 4 + 128);
    float bv[2][4] = {{bb0.x, bb0.y, bb0.z, bb0.w}, {bb1.x, bb1.y, bb1.z, bb1.w}};
#pragma unroll
    for (int i = 0; i < 4; ++i)
#pragma unroll
      for (int j = 0; j < 2; ++j) {
        float4 v;
        float vv[4];
#pragma unroll
        for (int c = 0; c < 4; ++c) {
          float x = acc[i][j][c] + bv[j][c];
          vv[c] = x > 0.0f ? x : 0.01f * x;
        }
        v.x = vv[0]; v.y = vv[1]; v.z = vv[2]; v.w = vv[3];
        *(float4*)(&Xb[rg * 4 + i][cg * 4 + j * 128]) = v;
      }
  }
  __syncthreads();

  // ===================== layer 3: Xa = Xb @ W3^T + b3 =====================
#pragma unroll
  for (int i = 0; i < 4; ++i)
#pragma unroll
    for (int j = 0; j < 2; ++j)
#pragma unroll
      for (int c = 0; c < 4; ++c) acc[i][j][c] = 0.0f;

  for (int d0 = 0; d0 < KC; d0 += 8) {
    const float4* wsrc = (const float4*)(W3T + (size_t)d0 * KC);
    float4* wdst = (float4*)(&Wt[0][0]);
    wdst[t] = wsrc[t];
    wdst[t + 256] = wsrc[t + 256];
    __syncthreads();
#pragma unroll
    for (int dd = 0; dd < 8; ++dd) {
      const int d = d0 + dd;
      float ev[4];
#pragma unroll
      for (int i = 0; i < 4; ++i) ev[i] = Xb[rg * 4 + i][d];
      float4 w0 = *(const float4*)(&Wt[dd][cg * 4]);
      float4 w1 = *(const float4*)(&Wt[dd][cg * 4 + 128]);
      float wv[2][4] = {{w0.x, w0.y, w0.z, w0.w}, {w1.x, w1.y, w1.z, w1.w}};
#pragma unroll
      for (int i = 0; i < 4; ++i)
#pragma unroll
        for (int j = 0; j < 2; ++j)
#pragma unroll
          for (int c = 0; c < 4; ++c)
            acc[i][j][c] = fmaf(ev[i], wv[j][c], acc[i][j][c]);
    }
    __syncthreads();
  }
  {
    float4 bb0 = *(const float4*)(b3 + cg * 4);
    float4 bb1 = *(const float4*)(b3 + cg * 4 + 128);
    float bv[2][4] = {{bb0.x, bb0.y, bb0.z, bb0.w}, {bb1.x, bb1.y, bb1.z, bb1.w}};
#pragma unroll
    for (int i = 0; i < 4; ++i)
#pragma unroll
      for (int j = 0; j < 2; ++j) {
        float4 v;
        v.x = acc[i][j][0] + bv[j][0];
        v.y = acc[i][j][1] + bv[j][1];
        v.z = acc[i][j][2] + bv[j][2];
        v.w = acc[i][j][3] + bv[j][3];
        *(float4*)(&Xa[rg * 4 + i][cg * 4 + j * 128]) = v;
      }
  }
  __syncthreads();

  // ===================== softmax + argmax + gamma_sum partials =====================
  const int wv_ = t >> 6;   // wave 0..3
  const int lane = t & 63;
  float gacc[4] = {0.0f, 0.0f, 0.0f, 0.0f};
#pragma unroll 1
  for (int rr = 0; rr < 8; ++rr) {
    const int row = wv_ * 8 + rr;
    float4 x4 = *(const float4*)(&Xa[row][lane * 4]);
    float xv[4] = {x4.x, x4.y, x4.z, x4.w};
    float bvv = xv[0];
    int bi = lane * 4;
#pragma unroll
    for (int c = 1; c < 4; ++c)
      if (xv[c] > bvv) { bvv = xv[c]; bi = lane * 4 + c; }
#pragma unroll
    for (int off = 32; off > 0; off >>= 1) {
      float ov = __shfl_xor(bvv, off, 64);
      int oi = __shfl_xor(bi, off, 64);
      if (ov > bvv || (ov == bvv && oi < bi)) { bvv = ov; bi = oi; }
    }
    float p[4];
    float ps = 0.0f;
#pragma unroll
    for (int c = 0; c < 4; ++c) { p[c] = expf(xv[c] - bvv); ps += p[c]; }
#pragma unroll
    for (int off = 32; off > 0; off >>= 1) ps += __shfl_xor(ps, off, 64);
    const float rs = 1.0f / ps;
    float4 o4;
    float gv[4];
#pragma unroll
    for (int c = 0; c < 4; ++c) { gv[c] = p[c] * rs; gacc[c] += gv[c]; }
    o4.x = gv[0]; o4.y = gv[1]; o4.z = gv[2]; o4.w = gv[3];
    *(float4*)(gamma + (rbase + row) * KC + lane * 4) = o4;
    if (lane == 0) idx_out[rbase + row] = (float)bi;
  }
#pragma unroll
  for (int c = 0; c < 4; ++c) atomicAdd(&gs[lane * 4 + c], gacc[c]);
  __syncthreads();
  gsp[(size_t)blk * KC + t] = gs[t];
}

// ---------------- gamma_sum reduce: gsp[6250][256] -> gsum[256] ----------------
__global__ __launch_bounds__(256) void gsum_reduce_kernel(const float* __restrict__ gsp,
                                                          float* __restrict__ gsum) {
  const int b = blockIdx.x;   // 0..24
  const int k = threadIdx.x;  // 0..255
  float s = 0.0f;
  for (int i = 0; i < 250; ++i) s += gsp[(size_t)(b * 250 + i) * KC + k];
  atomicAdd(&gsum[k], s);
}

// ---------------- KL: sum over rows of  s1 - s2 + lse(y) ----------------
__global__ __launch_bounds__(256) void kl_kernel(const float* __restrict__ gamma,
                                                 const float* __restrict__ gsum,
                                                 float* __restrict__ out_kl) {
  const int t = threadIdx.x;
  const int wv_ = t >> 6;
  const int lane = t & 63;
  __shared__ float wsum[4];
  float4 g4 = *(const float4*)(gsum + lane * 4);
  float rg[4] = {1.0f / g4.x, 1.0f / g4.y, 1.0f / g4.z, 1.0f / g4.w};
  const size_t base_row = (size_t)blockIdx.x * 64 + (size_t)wv_ * 16;
  float kacc = 0.0f;
#pragma unroll 1
  for (int rr = 0; rr < 16; ++rr) {
    const size_t row = base_row + rr;
    float4 x4 = *(const float4*)(gamma + row * KC + lane * 4);
    float g[4] = {x4.x, x4.y, x4.z, x4.w};
    float y[4];
    float s12 = 0.0f;
    float my = -1e30f;
#pragma unroll
    for (int c = 0; c < 4; ++c) {
      y[c] = g[c] * g[c] * rg[c];
      my = fmaxf(my, y[c]);
      s12 += (g[c] > 0.0f ? g[c] * logf(g[c]) : 0.0f) - g[c] * y[c];
    }
#pragma unroll
    for (int off = 32; off > 0; off >>= 1) my = fmaxf(my, __shfl_xor(my, off, 64));
    float es = 0.0f;
#pragma unroll
    for (int c = 0; c < 4; ++c) es += expf(y[c] - my);
#pragma unroll
    for (int off = 32; off > 0; off >>= 1) es += __shfl_xor(es, off, 64);
#pragma unroll
    for (int off = 32; off > 0; off >>= 1) s12 += __shfl_xor(s12, off, 64);
    kacc += s12 + my + logf(es);
  }
  if (lane == 0) wsum[wv_] = kacc;
  __syncthreads();
  if (t == 0) atomicAdd(out_kl, wsum[0] + wsum[1] + wsum[2] + wsum[3]);
}

// ---------------- mean pass 1: per-chunk partial of gamma^T @ E ----------------
// grid.x = 8 tiles (2 k-tiles x 4 d-tiles of 128x128), grid.y = NCHUNKS
__global__ __launch_bounds__(256) void mean_pass1(const float* __restrict__ gamma,
                                                  const float* __restrict__ E,
                                                  float* __restrict__ partial) {
  __shared__ float Gt[8][128];
  __shared__ float Et[8][128];
  const int t = threadIdx.x;
  const int tile = blockIdx.x;
  const int kb = (tile >> 2) * 128;
  const int db = (tile & 3) * 128;
  const int chunk = blockIdx.y;
  const size_t n0 = (size_t)chunk * NCHUNK;
  const int kq = t >> 4;   // 0..15
  const int dq = t & 15;   // 0..15
  float acc[2][2][4][4];
#pragma unroll
  for (int a = 0; a < 2; ++a)
#pragma unroll
    for (int b = 0; b < 2; ++b)
#pragma unroll
      for (int c = 0; c < 4; ++c)
#pragma unroll
        for (int d = 0; d < 4; ++d) acc[a][b][c][d] = 0.0f;

  const int sr = t >> 5;          // 0..7
  const int sc = (t & 31) * 4;    // 0..124
  for (size_t n = n0; n < n0 + NCHUNK; n += 8) {
    *(float4*)(&Gt[sr][sc]) = *(const float4*)(gamma + (n + sr) * KC + kb + sc);
    *(float4*)(&Et[sr][sc]) = *(const float4*)(E + (n + sr) * DIM + db + sc);
    __syncthreads();
#pragma unroll
    for (int nn = 0; nn < 8; ++nn) {
      float4 a0 = *(const float4*)(&Gt[nn][kq * 4]);
      float4 a1 = *(const float4*)(&Gt[nn][kq * 4 + 64]);
      float4 c0 = *(const float4*)(&Et[nn][dq * 4]);
      float4 c1 = *(const float4*)(&Et[nn][dq * 4 + 64]);
      float ga[2][4] = {{a0.x, a0.y, a0.z, a0.w}, {a1.x, a1.y, a1.z, a1.w}};
      float ea[2][4] = {{c0.x, c0.y, c0.z, c0.w}, {c1.x, c1.y, c1.z, c1.w}};
#pragma unroll
      for (int jk = 0; jk < 2; ++jk)
#pragma unroll
        for (int jd = 0; jd < 2; ++jd)
#pragma unroll
          for (int ck = 0; ck < 4; ++ck)
#pragma unroll
            for (int cd = 0; cd < 4; ++cd)
              acc[jk][jd][ck][cd] = fmaf(ga[jk][ck], ea[jd][cd], acc[jk][jd][ck][cd]);
    }
    __syncthreads();
  }
  const size_t pbase = (size_t)chunk * (KC * DIM);
#pragma unroll
  for (int jk = 0; jk < 2; ++jk)
#pragma unroll
    for (int ck = 0; ck < 4; ++ck)
#pragma unroll
      for (int jd = 0; jd < 2; ++jd) {
        const int k = kb + kq * 4 + ck + 64 * jk;
        const int d = db + dq * 4 + 64 * jd;
        float4 v;
        v.x = acc[jk][jd][ck][0];
        v.y = acc[jk][jd][ck][1];
        v.z = acc[jk][jd][ck][2];
        v.w = acc[jk][jd][ck][3];
        *(float4*)(partial + pbase + (size_t)k * DIM + d) = v;
      }
}

// ---------------- mean pass 2: reduce chunks, divide by gamma_sum ----------------
__global__ __launch_bounds__(256) void mean_pass2(const float* __restrict__ partial,
                                                  const float* __restrict__ gsum,
                                                  float* __restrict__ out_mean) {
  const int t = blockIdx.x * 256 + threadIdx.x;  // 0..131071
  float s = 0.0f;
  for (int c = 0; c < NCHUNKS; ++c) s += partial[(size_t)c * (KC * DIM) + t];
  out_mean[t] = s / gsum[t >> 9];
}

extern "C" void kernel_launch(void* const* d_in, const int* in_sizes, int n_in,
                              void* d_out, int out_size, void* d_ws, size_t ws_size,
                              hipStream_t stream) {
  const float* E  = (const float*)d_in[0];
  const float* W1 = (const float*)d_in[1];
  const float* b1 = (const float*)d_in[2];
  const float* W2 = (const float*)d_in[3];
  const float* b2 = (const float*)d_in[4];
  const float* W3 = (const float*)d_in[5];
  const float* b3 = (const float*)d_in[6];
  float* out = (float*)d_out;  // [0]=kl, [1..N]=indices(float), [1+N ..]=mean[K][D]

  float* ws = (float*)d_ws;
  float* gamma = ws;                                  // 51,200,000
  float* gsp   = gamma + (size_t)NROWS * KC;          //  1,600,000
  float* gsum  = gsp + (size_t)(NROWS / 32) * KC;     //        256
  float* w1t   = gsum + KC;                           //    131,072
  float* w2t   = w1t + DIM * KC;                      //     65,536
  float* w3t   = w2t + KC * KC;                       //     65,536
  float* mpart = w3t + KC * KC;                       // 13,107,200

  hipMemsetAsync(d_out, 0, sizeof(float), stream);        // kl accumulator
  hipMemsetAsync(gsum, 0, KC * sizeof(float), stream);    // gamma_sum accumulator

  transpose_kernel<<<dim3(DIM / 32, KC / 32), dim3(32, 8), 0, stream>>>(W1, w1t, KC, DIM);
  transpose_kernel<<<dim3(KC / 32, KC / 32), dim3(32, 8), 0, stream>>>(W2, w2t, KC, KC);
  transpose_kernel<<<dim3(KC / 32, KC / 32), dim3(32, 8), 0, stream>>>(W3, w3t, KC, KC);

  mlp_softmax_kernel<<<NROWS / 32, 256, 0, stream>>>(E, w1t, w2t, w3t, b1, b2, b3,
                                                     gamma, out + 1, gsp);
  gsum_reduce_kernel<<<25, 256, 0, stream>>>(gsp, gsum);
  kl_kernel<<<NROWS / 64, 256, 0, stream>>>(gamma, gsum, out);
  mean_pass1<<<dim3(8, NCHUNKS), 256, 0, stream>>>(gamma, E, mpart);
  mean_pass2<<<(KC * DIM) / 256, 256, 0, stream>>>(mpart, gsum, out + 1 + NROWS);
}

// Round 2
// 2397.468 us; speedup vs baseline: 1.1823x; 1.1823x over previous
//
#include <hip/hip_runtime.h>
#include <math.h>

#define NROWS 200000
#define DIM   512
#define KC    256
#define NCHUNKS 50
#define NCHUNK  4000   // rows per mean chunk (50*4000 = 200000)
#define NBLK_MLP 2500  // 200000 / 80
#define MARGIN 0.0625f

typedef float f32x4 __attribute__((ext_vector_type(4)));
typedef short short8v __attribute__((ext_vector_type(8)));
typedef short short4v __attribute__((ext_vector_type(4)));

__device__ inline short f2bs(float f) {            // f32 -> bf16 bits (RNE)
  unsigned u = __float_as_uint(f);
  unsigned r = (u + 0x7FFFu + ((u >> 16) & 1u)) >> 16;
  return (short)r;
}
__device__ inline float bs2f(short s) {            // bf16 bits -> f32 (exact)
  return __uint_as_float(((unsigned)(unsigned short)s) << 16);
}

// ---------------- transpose: src[R][C] -> dst[C][R] (f32, for recompute weights) ----
__global__ __launch_bounds__(256) void transpose_kernel(const float* __restrict__ src,
                                                        float* __restrict__ dst,
                                                        int R, int C) {
  __shared__ float tile[32][33];
  const int tx = threadIdx.x;
  const int ty = threadIdx.y;
  const int c0 = blockIdx.x * 32;
  const int r0 = blockIdx.y * 32;
#pragma unroll
  for (int j = 0; j < 32; j += 8)
    tile[ty + j][tx] = src[(size_t)(r0 + ty + j) * C + c0 + tx];
  __syncthreads();
#pragma unroll
  for (int j = 0; j < 32; j += 8)
    dst[(size_t)(c0 + ty + j) * R + r0 + tx] = tile[tx][ty + j];
}

// ---------------- pack W (f32 [Kout=256][Kin]) into bf16 B-fragment order -------------
// P[((nf*KS + ks)*64 + lane)*8 + j] = bf16( W[nf*16 + (lane&15)][ks*32 + (lane>>4)*8 + j] )
__global__ __launch_bounds__(256) void packW_kernel(const float* __restrict__ W,
                                                    short* __restrict__ P, int Kin) {
  const int KS = Kin >> 5;
  const int total = 16 * KS * 64;
  int tid = blockIdx.x * 256 + threadIdx.x;
  if (tid >= total) return;
  const int l = tid & 63;
  const int ks = (tid >> 6) % KS;
  const int nf = tid / (64 * KS);
  const float* src = W + (size_t)(nf * 16 + (l & 15)) * Kin + ks * 32 + (l >> 4) * 8;
  short8v v;
#pragma unroll
  for (int j = 0; j < 8; ++j) v[j] = f2bs(src[j]);
  *(short8v*)(P + (size_t)tid * 8) = v;
}

// ---------------- fused bf16-MFMA MLP + softmax + argmax + tie detection --------------
// 256 threads = 4 waves (wc = col-quarter). Block owns 80 rows x 256 cols.
// Wave tile: 80 x 64 -> acc[5 m][4 n] frags of mfma_f32_16x16x32_bf16.
// A-frag: row = lane&15 (+16m), k = 8*(lane>>4)+j.  B-frag from packed W (direct global).
// C/D: col = lane&15, row = 4*(lane>>4) + reg.
__global__ __launch_bounds__(256, 2) void mlp_mfma_kernel(
    const float* __restrict__ E,
    const short* __restrict__ PW1, const short* __restrict__ PW2,
    const short* __restrict__ PW3,
    const float* __restrict__ b1, const float* __restrict__ b2,
    const float* __restrict__ b3,
    short* __restrict__ gamma, float* __restrict__ idx_out,
    float* __restrict__ gsp, int* __restrict__ tiecnt, int* __restrict__ tielist) {
  __shared__ __align__(16) short X[80 * 256];   // 40KB, XOR-swizzled bf16 activations
  __shared__ float redV[4][80];
  __shared__ float redI[4][80];
  __shared__ float red2[4][80];
  __shared__ float rowM[80];
  __shared__ float rowS[80];
  __shared__ int lrows[80];
  __shared__ int lcnt;
  __shared__ int gbase;

  const int t = threadIdx.x;
  const int blk = blockIdx.x;
  const int wc = t >> 6;        // wave = col quarter
  const int lane = t & 63;
  const int lo = lane & 15;
  const int q = lane >> 4;

  if (t == 0) lcnt = 0;

  f32x4 acc[5][4];

  // ===== layer 1: acc = E @ W1^T  (A from global f32 E, cvt in-reg; B from packed) =====
#pragma unroll
  for (int m = 0; m < 5; ++m)
#pragma unroll
    for (int n = 0; n < 4; ++n) acc[m][n] = (f32x4){0.f, 0.f, 0.f, 0.f};

  const float* e0 = E + (size_t)(blk * 80 + lo) * DIM + q * 8;
#pragma unroll
  for (int ks = 0; ks < 16; ++ks) {
    short8v a[5];
#pragma unroll
    for (int m = 0; m < 5; ++m) {
      const float* ep = e0 + m * 16 * DIM + ks * 32;
      float4 x0 = *(const float4*)ep;
      float4 x1 = *(const float4*)(ep + 4);
      short8v av;
      av[0] = f2bs(x0.x); av[1] = f2bs(x0.y); av[2] = f2bs(x0.z); av[3] = f2bs(x0.w);
      av[4] = f2bs(x1.x); av[5] = f2bs(x1.y); av[6] = f2bs(x1.z); av[7] = f2bs(x1.w);
      a[m] = av;
    }
#pragma unroll
    for (int n = 0; n < 4; ++n) {
      short8v b = *(const short8v*)(PW1 + ((size_t)((wc * 4 + n) * 16 + ks) * 64 + lane) * 8);
#pragma unroll
      for (int m = 0; m < 5; ++m)
        acc[m][n] = __builtin_amdgcn_mfma_f32_16x16x32_bf16(a[m], b, acc[m][n], 0, 0, 0);
    }
  }
  {  // epilogue 1: bias + leaky -> X (swizzled bf16)
    float bc[4];
#pragma unroll
    for (int n = 0; n < 4; ++n) bc[n] = b1[wc * 64 + n * 16 + lo];
#pragma unroll
    for (int m = 0; m < 5; ++m)
#pragma unroll
      for (int j = 0; j < 4; ++j) {
        const int row = m * 16 + 4 * q + j;
#pragma unroll
        for (int n = 0; n < 4; ++n) {
          float v = acc[m][n][j] + bc[n];
          v = v > 0.f ? v : 0.01f * v;
          const int col = wc * 64 + n * 16 + lo;
          X[row * 256 + ((((col >> 3) ^ (row & 7)) << 3) | (col & 7))] = f2bs(v);
        }
      }
  }
  __syncthreads();

  // ===== layer 2 =====
#pragma unroll
  for (int m = 0; m < 5; ++m)
#pragma unroll
    for (int n = 0; n < 4; ++n) acc[m][n] = (f32x4){0.f, 0.f, 0.f, 0.f};
#pragma unroll
  for (int ks = 0; ks < 8; ++ks) {
    short8v a[5];
#pragma unroll
    for (int m = 0; m < 5; ++m) {
      const int row = m * 16 + lo;
      const int ck = (ks * 4 + q) ^ (row & 7);
      a[m] = *(const short8v*)&X[row * 256 + ck * 8];
    }
#pragma unroll
    for (int n = 0; n < 4; ++n) {
      short8v b = *(const short8v*)(PW2 + ((size_t)((wc * 4 + n) * 8 + ks) * 64 + lane) * 8);
#pragma unroll
      for (int m = 0; m < 5; ++m)
        acc[m][n] = __builtin_amdgcn_mfma_f32_16x16x32_bf16(a[m], b, acc[m][n], 0, 0, 0);
    }
  }
  __syncthreads();  // all X1 reads done
  {  // epilogue 2
    float bc[4];
#pragma unroll
    for (int n = 0; n < 4; ++n) bc[n] = b2[wc * 64 + n * 16 + lo];
#pragma unroll
    for (int m = 0; m < 5; ++m)
#pragma unroll
      for (int j = 0; j < 4; ++j) {
        const int row = m * 16 + 4 * q + j;
#pragma unroll
        for (int n = 0; n < 4; ++n) {
          float v = acc[m][n][j] + bc[n];
          v = v > 0.f ? v : 0.01f * v;
          const int col = wc * 64 + n * 16 + lo;
          X[row * 256 + ((((col >> 3) ^ (row & 7)) << 3) | (col & 7))] = f2bs(v);
        }
      }
  }
  __syncthreads();

  // ===== layer 3 (logits stay in acc) =====
#pragma unroll
  for (int m = 0; m < 5; ++m)
#pragma unroll
    for (int n = 0; n < 4; ++n) acc[m][n] = (f32x4){0.f, 0.f, 0.f, 0.f};
#pragma unroll
  for (int ks = 0; ks < 8; ++ks) {
    short8v a[5];
#pragma unroll
    for (int m = 0; m < 5; ++m) {
      const int row = m * 16 + lo;
      const int ck = (ks * 4 + q) ^ (row & 7);
      a[m] = *(const short8v*)&X[row * 256 + ck * 8];
    }
#pragma unroll
    for (int n = 0; n < 4; ++n) {
      short8v b = *(const short8v*)(PW3 + ((size_t)((wc * 4 + n) * 8 + ks) * 64 + lane) * 8);
#pragma unroll
      for (int m = 0; m < 5; ++m)
        acc[m][n] = __builtin_amdgcn_mfma_f32_16x16x32_bf16(a[m], b, acc[m][n], 0, 0, 0);
    }
  }
  {  // + b3
    float bc[4];
#pragma unroll
    for (int n = 0; n < 4; ++n) bc[n] = b3[wc * 64 + n * 16 + lo];
#pragma unroll
    for (int m = 0; m < 5; ++m)
#pragma unroll
      for (int n = 0; n < 4; ++n)
#pragma unroll
        for (int j = 0; j < 4; ++j) acc[m][n][j] += bc[n];
  }

  // ===== phase A: per-row wave-slice top2 + argmax (16-lane shfl reduce) =====
#pragma unroll
  for (int m = 0; m < 5; ++m)
#pragma unroll
    for (int j = 0; j < 4; ++j) {
      const int r = m * 16 + 4 * q + j;
      float mx = acc[m][0][j];
      int mi = wc * 64 + lo;
      float m2 = -3.4e38f;
#pragma unroll
      for (int n = 1; n < 4; ++n) {
        float v = acc[m][n][j];
        int c = wc * 64 + n * 16 + lo;
        if (v > mx) { m2 = mx; mx = v; mi = c; }
        else if (v > m2) m2 = v;
      }
#pragma unroll
      for (int off = 1; off < 16; off <<= 1) {
        float ov = __shfl_xor(mx, off, 64);
        int oi = __shfl_xor(mi, off, 64);
        float o2 = __shfl_xor(m2, off, 64);
        float nm2 = fmaxf(m2, o2);
        if (ov > mx) { nm2 = fmaxf(nm2, mx); mx = ov; mi = oi; }
        else { nm2 = fmaxf(nm2, ov); if (ov == mx && oi < mi) mi = oi; }
        m2 = nm2;
      }
      if (lo == 0) { redV[wc][r] = mx; redI[wc][r] = __int_as_float(mi); red2[wc][r] = m2; }
    }
  __syncthreads();

  // ===== phase B: finalize max/argmax/top2 per row, flag ties =====
  if (t < 80) {
    float gm = -3.4e38f, g2 = -3.4e38f;
    int gi = 0;
#pragma unroll
    for (int w = 0; w < 4; ++w) {
      float v = redV[w][t];
      int i2 = __float_as_int(redI[w][t]);
      float s2 = red2[w][t];
      if (v > gm) { g2 = fmaxf(fmaxf(g2, gm), s2); gm = v; gi = i2; }
      else { if (v == gm && i2 < gi) gi = i2; g2 = fmaxf(g2, v); }
    }
    rowM[t] = gm;
    idx_out[(size_t)blk * 80 + t] = (float)gi;
    if (gm - g2 < MARGIN) { int p = atomicAdd(&lcnt, 1); lrows[p] = blk * 80 + t; }
  }
  __syncthreads();

  // ===== phase C: exp + row sums =====
#pragma unroll
  for (int m = 0; m < 5; ++m)
#pragma unroll
    for (int j = 0; j < 4; ++j) {
      const int r = m * 16 + 4 * q + j;
      const float gm = rowM[r];
      float s = 0.f;
#pragma unroll
      for (int n = 0; n < 4; ++n) {
        float e = expf(acc[m][n][j] - gm);
        acc[m][n][j] = e;
        s += e;
      }
#pragma unroll
      for (int off = 1; off < 16; off <<= 1) s += __shfl_xor(s, off, 64);
      if (lo == 0) redV[wc][r] = s;
    }
  __syncthreads();
  if (t < 80) rowS[t] = redV[0][t] + redV[1][t] + redV[2][t] + redV[3][t];
  __syncthreads();

  // ===== phase D: gamma -> X (swizzled bf16), column partial sums =====
  float csum[4] = {0.f, 0.f, 0.f, 0.f};
#pragma unroll
  for (int m = 0; m < 5; ++m)
#pragma unroll
    for (int j = 0; j < 4; ++j) {
      const int r = m * 16 + 4 * q + j;
      const float inv = 1.0f / rowS[r];
#pragma unroll
      for (int n = 0; n < 4; ++n) {
        float g = acc[m][n][j] * inv;
        csum[n] += g;
        const int col = wc * 64 + n * 16 + lo;
        X[r * 256 + ((((col >> 3) ^ (r & 7)) << 3) | (col & 7))] = f2bs(g);
      }
    }
#pragma unroll
  for (int n = 0; n < 4; ++n) {
    csum[n] += __shfl_xor(csum[n], 16, 64);
    csum[n] += __shfl_xor(csum[n], 32, 64);
  }
  if (q == 0) {
#pragma unroll
    for (int n = 0; n < 4; ++n)
      gsp[(size_t)blk * KC + wc * 64 + n * 16 + lo] = csum[n];
  }
  __syncthreads();

  // copy X -> gamma (global, coalesced 16B)
#pragma unroll
  for (int pass = 0; pass < 10; ++pass) {
    const int rr = pass * 8 + (t >> 5);
    const int cid = t & 31;
    short8v v = *(const short8v*)&X[rr * 256 + ((cid ^ (rr & 7)) << 3)];
    *(short8v*)(gamma + (size_t)(blk * 80 + rr) * KC + cid * 8) = v;
  }

  // flush tie list
  if (t == 0 && lcnt > 0) gbase = atomicAdd(tiecnt, lcnt);
  __syncthreads();
  if (t < lcnt) tielist[gbase + t] = lrows[t];
}

// ---------------- exact f32 recompute of flagged rows (argmax only) -------------------
__global__ __launch_bounds__(256, 2) void recompute_kernel(
    const float* __restrict__ E,
    const float* __restrict__ W1T, const float* __restrict__ W2T,
    const float* __restrict__ W3T,
    const float* __restrict__ b1, const float* __restrict__ b2,
    const float* __restrict__ b3,
    const int* __restrict__ tiecnt, const int* __restrict__ tielist,
    float* __restrict__ idx_out) {
  __shared__ float Xa[32][KC];
  __shared__ float Xb[32][KC];
  __shared__ float Wt[8][KC];
  __shared__ float Et[8][32];
  __shared__ int rid[32];

  const int t = threadIdx.x;
  const int cg = t & 31;
  const int rg = t >> 5;
  const int cnt = *tiecnt;

  for (int base = blockIdx.x * 32; base < cnt; base += gridDim.x * 32) {
    const int nr = min(32, cnt - base);
    if (t < 32) rid[t] = tielist[base + min(t, nr - 1)];
    __syncthreads();

    float acc[4][2][4];
    // ---- layer 1 ----
#pragma unroll
    for (int i = 0; i < 4; ++i)
#pragma unroll
      for (int j = 0; j < 2; ++j)
#pragma unroll
        for (int c = 0; c < 4; ++c) acc[i][j][c] = 0.0f;
    for (int d0 = 0; d0 < DIM; d0 += 8) {
      const float4* wsrc = (const float4*)(W1T + (size_t)d0 * KC);
      float4* wdst = (float4*)(&Wt[0][0]);
      wdst[t] = wsrc[t];
      wdst[t + 256] = wsrc[t + 256];
      Et[t & 7][t >> 3] = E[(size_t)rid[t >> 3] * DIM + d0 + (t & 7)];
      __syncthreads();
#pragma unroll
      for (int dd = 0; dd < 8; ++dd) {
        float4 e4 = *(const float4*)(&Et[dd][rg * 4]);
        float4 w0 = *(const float4*)(&Wt[dd][cg * 4]);
        float4 w1 = *(const float4*)(&Wt[dd][cg * 4 + 128]);
        float ev[4] = {e4.x, e4.y, e4.z, e4.w};
        float wv[2][4] = {{w0.x, w0.y, w0.z, w0.w}, {w1.x, w1.y, w1.z, w1.w}};
#pragma unroll
        for (int i = 0; i < 4; ++i)
#pragma unroll
          for (int j = 0; j < 2; ++j)
#pragma unroll
            for (int c = 0; c < 4; ++c)
              acc[i][j][c] = fmaf(ev[i], wv[j][c], acc[i][j][c]);
      }
      __syncthreads();
    }
    {
      float4 bb0 = *(const float4*)(b1 + cg * 4);
      float4 bb1 = *(const float4*)(b1 + cg * 4 + 128);
      float bv[2][4] = {{bb0.x, bb0.y, bb0.z, bb0.w}, {bb1.x, bb1.y, bb1.z, bb1.w}};
#pragma unroll
      for (int i = 0; i < 4; ++i)
#pragma unroll
        for (int j = 0; j < 2; ++j) {
          float4 v;
          float vv[4];
#pragma unroll
          for (int c = 0; c < 4; ++c) {
            float x = acc[i][j][c] + bv[j][c];
            vv[c] = x > 0.0f ? x : 0.01f * x;
          }
          v.x = vv[0]; v.y = vv[1]; v.z = vv[2]; v.w = vv[3];
          *(float4*)(&Xa[rg * 4 + i][cg * 4 + j * 128]) = v;
        }
    }
    __syncthreads();
    // ---- layer 2 ----
#pragma unroll
    for (int i = 0; i < 4; ++i)
#pragma unroll
      for (int j = 0; j < 2; ++j)
#pragma unroll
        for (int c = 0; c < 4; ++c) acc[i][j][c] = 0.0f;
    for (int d0 = 0; d0 < KC; d0 += 8) {
      const float4* wsrc = (const float4*)(W2T + (size_t)d0 * KC);
      float4* wdst = (float4*)(&Wt[0][0]);
      wdst[t] = wsrc[t];
      wdst[t + 256] = wsrc[t + 256];
      __syncthreads();
#pragma unroll
      for (int dd = 0; dd < 8; ++dd) {
        const int d = d0 + dd;
        float ev[4];
#pragma unroll
        for (int i = 0; i < 4; ++i) ev[i] = Xa[rg * 4 + i][d];
        float4 w0 = *(const float4*)(&Wt[dd][cg * 4]);
        float4 w1 = *(const float4*)(&Wt[dd][cg * 4 + 128]);
        float wv[2][4] = {{w0.x, w0.y, w0.z, w0.w}, {w1.x, w1.y, w1.z, w1.w}};
#pragma unroll
        for (int i = 0; i < 4; ++i)
#pragma unroll
          for (int j = 0; j < 2; ++j)
#pragma unroll
            for (int c = 0; c < 4; ++c)
              acc[i][j][c] = fmaf(ev[i], wv[j][c], acc[i][j][c]);
      }
      __syncthreads();
    }
    {
      float4 bb0 = *(const float4*)(b2 + cg * 4);
      float4 bb1 = *(const float4*)(b2 + cg * 4 + 128);
      float bv[2][4] = {{bb0.x, bb0.y, bb0.z, bb0.w}, {bb1.x, bb1.y, bb1.z, bb1.w}};
#pragma unroll
      for (int i = 0; i < 4; ++i)
#pragma unroll
        for (int j = 0; j < 2; ++j) {
          float4 v;
          float vv[4];
#pragma unroll
          for (int c = 0; c < 4; ++c) {
            float x = acc[i][j][c] + bv[j][c];
            vv[c] = x > 0.0f ? x : 0.01f * x;
          }
          v.x = vv[0]; v.y = vv[1]; v.z = vv[2]; v.w = vv[3];
          *(float4*)(&Xb[rg * 4 + i][cg * 4 + j * 128]) = v;
        }
    }
    __syncthreads();
    // ---- layer 3 ----
#pragma unroll
    for (int i = 0; i < 4; ++i)
#pragma unroll
      for (int j = 0; j < 2; ++j)
#pragma unroll
        for (int c = 0; c < 4; ++c) acc[i][j][c] = 0.0f;
    for (int d0 = 0; d0 < KC; d0 += 8) {
      const float4* wsrc = (const float4*)(W3T + (size_t)d0 * KC);
      float4* wdst = (float4*)(&Wt[0][0]);
      wdst[t] = wsrc[t];
      wdst[t + 256] = wsrc[t + 256];
      __syncthreads();
#pragma unroll
      for (int dd = 0; dd < 8; ++dd) {
        const int d = d0 + dd;
        float ev[4];
#pragma unroll
        for (int i = 0; i < 4; ++i) ev[i] = Xb[rg * 4 + i][d];
        float4 w0 = *(const float4*)(&Wt[dd][cg * 4]);
        float4 w1 = *(const float4*)(&Wt[dd][cg * 4 + 128]);
        float wv[2][4] = {{w0.x, w0.y, w0.z, w0.w}, {w1.x, w1.y, w1.z, w1.w}};
#pragma unroll
        for (int i = 0; i < 4; ++i)
#pragma unroll
          for (int j = 0; j < 2; ++j)
#pragma unroll
            for (int c = 0; c < 4; ++c)
              acc[i][j][c] = fmaf(ev[i], wv[j][c], acc[i][j][c]);
      }
      __syncthreads();
    }
    {
      float4 bb0 = *(const float4*)(b3 + cg * 4);
      float4 bb1 = *(const float4*)(b3 + cg * 4 + 128);
      float bv[2][4] = {{bb0.x, bb0.y, bb0.z, bb0.w}, {bb1.x, bb1.y, bb1.z, bb1.w}};
#pragma unroll
      for (int i = 0; i < 4; ++i)
#pragma unroll
        for (int j = 0; j < 2; ++j) {
          float4 v;
          v.x = acc[i][j][0] + bv[j][0];
          v.y = acc[i][j][1] + bv[j][1];
          v.z = acc[i][j][2] + bv[j][2];
          v.w = acc[i][j][3] + bv[j][3];
          *(float4*)(&Xa[rg * 4 + i][cg * 4 + j * 128]) = v;
        }
    }
    __syncthreads();
    // ---- argmax per row ----
    const int wv_ = t >> 6;
    const int lane = t & 63;
#pragma unroll 1
    for (int rr = 0; rr < 8; ++rr) {
      const int lr = wv_ * 8 + rr;
      float4 x4 = *(const float4*)(&Xa[lr][lane * 4]);
      float xv[4] = {x4.x, x4.y, x4.z, x4.w};
      float bvv = xv[0];
      int bi = lane * 4;
#pragma unroll
      for (int c = 1; c < 4; ++c)
        if (xv[c] > bvv) { bvv = xv[c]; bi = lane * 4 + c; }
#pragma unroll
      for (int off = 32; off > 0; off >>= 1) {
        float ov = __shfl_xor(bvv, off, 64);
        int oi = __shfl_xor(bi, off, 64);
        if (ov > bvv || (ov == bvv && oi < bi)) { bvv = ov; bi = oi; }
      }
      if (lane == 0 && lr < nr) idx_out[rid[lr]] = (float)bi;
    }
    __syncthreads();
  }
}

// ---------------- gamma_sum reduce: gsp[2500][256] -> gsum[256] ----------------
__global__ __launch_bounds__(256) void gsum_reduce_kernel(const float* __restrict__ gsp,
                                                          float* __restrict__ gsum) {
  const int b = blockIdx.x;   // 0..24
  const int k = threadIdx.x;
  float s = 0.0f;
  for (int i = 0; i < 100; ++i) s += gsp[(size_t)(b * 100 + i) * KC + k];
  atomicAdd(&gsum[k], s);
}

// ---------------- KL over bf16 gamma ----------------
__global__ __launch_bounds__(256) void kl_kernel(const short* __restrict__ gamma,
                                                 const float* __restrict__ gsum,
                                                 float* __restrict__ out_kl) {
  const int t = threadIdx.x;
  const int wv_ = t >> 6;
  const int lane = t & 63;
  __shared__ float wsum[4];
  float4 g4 = *(const float4*)(gsum + lane * 4);
  float rg[4] = {1.0f / g4.x, 1.0f / g4.y, 1.0f / g4.z, 1.0f / g4.w};
  const size_t base_row = (size_t)blockIdx.x * 64 + (size_t)wv_ * 16;
  float kacc = 0.0f;
#pragma unroll 1
  for (int rr = 0; rr < 16; ++rr) {
    const size_t row = base_row + rr;
    short4v s4 = *(const short4v*)(gamma + row * KC + lane * 4);
    float g[4] = {bs2f(s4[0]), bs2f(s4[1]), bs2f(s4[2]), bs2f(s4[3])};
    float y[4];
    float s12 = 0.0f;
    float my = -1e30f;
#pragma unroll
    for (int c = 0; c < 4; ++c) {
      y[c] = g[c] * g[c] * rg[c];
      my = fmaxf(my, y[c]);
      s12 += (g[c] > 0.0f ? g[c] * logf(g[c]) : 0.0f) - g[c] * y[c];
    }
#pragma unroll
    for (int off = 32; off > 0; off >>= 1) my = fmaxf(my, __shfl_xor(my, off, 64));
    float es = 0.0f;
#pragma unroll
    for (int c = 0; c < 4; ++c) es += expf(y[c] - my);
#pragma unroll
    for (int off = 32; off > 0; off >>= 1) es += __shfl_xor(es, off, 64);
#pragma unroll
    for (int off = 32; off > 0; off >>= 1) s12 += __shfl_xor(s12, off, 64);
    kacc += s12 + my + logf(es);
  }
  if (lane == 0) wsum[wv_] = kacc;
  __syncthreads();
  if (t == 0) atomicAdd(out_kl, wsum[0] + wsum[1] + wsum[2] + wsum[3]);
}

// ---------------- mean pass 1: per-chunk partial of gamma^T @ E (gamma bf16) ----------
__global__ __launch_bounds__(256) void mean_pass1(const short* __restrict__ gamma,
                                                  const float* __restrict__ E,
                                                  float* __restrict__ partial) {
  __shared__ float Gt[8][128];
  __shared__ float Et[8][128];
  const int t = threadIdx.x;
  const int tile = blockIdx.x;
  const int kb = (tile >> 2) * 128;
  const int db = (tile & 3) * 128;
  const int chunk = blockIdx.y;
  const size_t n0 = (size_t)chunk * NCHUNK;
  const int kq = t >> 4;
  const int dq = t & 15;
  float acc[2][2][4][4];
#pragma unroll
  for (int a = 0; a < 2; ++a)
#pragma unroll
    for (int b = 0; b < 2; ++b)
#pragma unroll
      for (int c = 0; c < 4; ++c)
#pragma unroll
        for (int d = 0; d < 4; ++d) acc[a][b][c][d] = 0.0f;

  const int sr = t >> 5;
  const int sc = (t & 31) * 4;
  for (size_t n = n0; n < n0 + NCHUNK; n += 8) {
    short4v g4 = *(const short4v*)(gamma + (n + sr) * KC + kb + sc);
    Gt[sr][sc + 0] = bs2f(g4[0]);
    Gt[sr][sc + 1] = bs2f(g4[1]);
    Gt[sr][sc + 2] = bs2f(g4[2]);
    Gt[sr][sc + 3] = bs2f(g4[3]);
    *(float4*)(&Et[sr][sc]) = *(const float4*)(E + (n + sr) * DIM + db + sc);
    __syncthreads();
#pragma unroll
    for (int nn = 0; nn < 8; ++nn) {
      float4 a0 = *(const float4*)(&Gt[nn][kq * 4]);
      float4 a1 = *(const float4*)(&Gt[nn][kq * 4 + 64]);
      float4 c0 = *(const float4*)(&Et[nn][dq * 4]);
      float4 c1 = *(const float4*)(&Et[nn][dq * 4 + 64]);
      float ga[2][4] = {{a0.x, a0.y, a0.z, a0.w}, {a1.x, a1.y, a1.z, a1.w}};
      float ea[2][4] = {{c0.x, c0.y, c0.z, c0.w}, {c1.x, c1.y, c1.z, c1.w}};
#pragma unroll
      for (int jk = 0; jk < 2; ++jk)
#pragma unroll
        for (int jd = 0; jd < 2; ++jd)
#pragma unroll
          for (int ck = 0; ck < 4; ++ck)
#pragma unroll
            for (int cd = 0; cd < 4; ++cd)
              acc[jk][jd][ck][cd] = fmaf(ga[jk][ck], ea[jd][cd], acc[jk][jd][ck][cd]);
    }
    __syncthreads();
  }
  const size_t pbase = (size_t)chunk * (KC * DIM);
#pragma unroll
  for (int jk = 0; jk < 2; ++jk)
#pragma unroll
    for (int ck = 0; ck < 4; ++ck)
#pragma unroll
      for (int jd = 0; jd < 2; ++jd) {
        const int k = kb + kq * 4 + ck + 64 * jk;
        const int d = db + dq * 4 + 64 * jd;
        float4 v;
        v.x = acc[jk][jd][ck][0];
        v.y = acc[jk][jd][ck][1];
        v.z = acc[jk][jd][ck][2];
        v.w = acc[jk][jd][ck][3];
        *(float4*)(partial + pbase + (size_t)k * DIM + d) = v;
      }
}

// ---------------- mean pass 2 ----------------
__global__ __launch_bounds__(256) void mean_pass2(const float* __restrict__ partial,
                                                  const float* __restrict__ gsum,
                                                  float* __restrict__ out_mean) {
  const int t = blockIdx.x * 256 + threadIdx.x;
  float s = 0.0f;
  for (int c = 0; c < NCHUNKS; ++c) s += partial[(size_t)c * (KC * DIM) + t];
  out_mean[t] = s / gsum[t >> 9];
}

extern "C" void kernel_launch(void* const* d_in, const int* in_sizes, int n_in,
                              void* d_out, int out_size, void* d_ws, size_t ws_size,
                              hipStream_t stream) {
  const float* E  = (const float*)d_in[0];
  const float* W1 = (const float*)d_in[1];
  const float* b1 = (const float*)d_in[2];
  const float* W2 = (const float*)d_in[3];
  const float* b2 = (const float*)d_in[4];
  const float* W3 = (const float*)d_in[5];
  const float* b3 = (const float*)d_in[6];
  float* out = (float*)d_out;  // [0]=kl, [1..N]=indices(float), [1+N..]=mean[K][D]

  char* p = (char*)d_ws;
  short* gamma = (short*)p;  p += (size_t)NROWS * KC * 2;          // 102.4 MB
  float* gsp   = (float*)p;  p += (size_t)NBLK_MLP * KC * 4;       // 2.56 MB
  float* gsum  = (float*)p;  p += KC * 4;
  short* pw1   = (short*)p;  p += (size_t)KC * DIM * 2;
  short* pw2   = (short*)p;  p += (size_t)KC * KC * 2;
  short* pw3   = (short*)p;  p += (size_t)KC * KC * 2;
  float* w1t   = (float*)p;  p += (size_t)DIM * KC * 4;
  float* w2t   = (float*)p;  p += (size_t)KC * KC * 4;
  float* w3t   = (float*)p;  p += (size_t)KC * KC * 4;
  int* tcnt    = (int*)p;    p += 256;
  int* tlist   = (int*)p;    p += (size_t)NROWS * 4;               // 0.8 MB
  float* mpart = (float*)p;  p += (size_t)NCHUNKS * KC * DIM * 4;  // 26.2 MB

  hipMemsetAsync(d_out, 0, sizeof(float), stream);
  hipMemsetAsync(gsum, 0, KC * sizeof(float), stream);
  hipMemsetAsync(tcnt, 0, sizeof(int), stream);

  packW_kernel<<<64, 256, 0, stream>>>(W1, pw1, DIM);
  packW_kernel<<<32, 256, 0, stream>>>(W2, pw2, KC);
  packW_kernel<<<32, 256, 0, stream>>>(W3, pw3, KC);
  transpose_kernel<<<dim3(DIM / 32, KC / 32), dim3(32, 8), 0, stream>>>(W1, w1t, KC, DIM);
  transpose_kernel<<<dim3(KC / 32, KC / 32), dim3(32, 8), 0, stream>>>(W2, w2t, KC, KC);
  transpose_kernel<<<dim3(KC / 32, KC / 32), dim3(32, 8), 0, stream>>>(W3, w3t, KC, KC);

  mlp_mfma_kernel<<<NBLK_MLP, 256, 0, stream>>>(E, pw1, pw2, pw3, b1, b2, b3,
                                                gamma, out + 1, gsp, tcnt, tlist);
  recompute_kernel<<<640, 256, 0, stream>>>(E, w1t, w2t, w3t, b1, b2, b3,
                                            tcnt, tlist, out + 1);
  gsum_reduce_kernel<<<25, 256, 0, stream>>>(gsp, gsum);
  kl_kernel<<<NROWS / 64, 256, 0, stream>>>(gamma, gsum, out);
  mean_pass1<<<dim3(8, NCHUNKS), 256, 0, stream>>>(gamma, E, mpart);
  mean_pass2<<<(KC * DIM) / 256, 256, 0, stream>>>(mpart, gsum, out + 1 + NROWS);
}

// Round 3
// 1999.068 us; speedup vs baseline: 1.4180x; 1.1993x over previous
//
#include <hip/hip_runtime.h>
#include <math.h>

#define NROWS 200000
#define DIM   512
#define KC    256
#define BM    64
#define NBLK_MLP (NROWS / BM)      // 3125
#define NSTEPS   (NROWS / 32)      // 6250
#define MCHUNKS  125
#define MSTEPS   (NSTEPS / MCHUNKS) // 50
#define MARGIN   0.0625f

typedef float f32x4 __attribute__((ext_vector_type(4)));
typedef short short8v __attribute__((ext_vector_type(8)));
typedef short short4v __attribute__((ext_vector_type(4)));

__device__ inline short f2bs(float f) {            // f32 -> bf16 bits (RNE)
  unsigned u = __float_as_uint(f);
  unsigned r = (u + 0x7FFFu + ((u >> 16) & 1u)) >> 16;
  return (short)r;
}
__device__ inline float bs2f(short s) {            // bf16 bits -> f32 (exact)
  return __uint_as_float(((unsigned)(unsigned short)s) << 16);
}

// ---------------- transpose: src[R][C] -> dst[C][R] (f32, recompute weights) ----------
__global__ __launch_bounds__(256) void transpose_kernel(const float* __restrict__ src,
                                                        float* __restrict__ dst,
                                                        int R, int C) {
  __shared__ float tile[32][33];
  const int tx = threadIdx.x;
  const int ty = threadIdx.y;
  const int c0 = blockIdx.x * 32;
  const int r0 = blockIdx.y * 32;
#pragma unroll
  for (int j = 0; j < 32; j += 8)
    tile[ty + j][tx] = src[(size_t)(r0 + ty + j) * C + c0 + tx];
  __syncthreads();
#pragma unroll
  for (int j = 0; j < 32; j += 8)
    dst[(size_t)(c0 + ty + j) * R + r0 + tx] = tile[tx][ty + j];
}

// ---------------- pack W (f32 [256][Kin]) into bf16 B-fragment order ------------------
// P[((nf*KS + ks)*64 + lane)*8 + j] = bf16( W[nf*16 + (lane&15)][ks*32 + (lane>>4)*8 + j] )
__global__ __launch_bounds__(256) void packW_kernel(const float* __restrict__ W,
                                                    short* __restrict__ P, int Kin) {
  const int KS = Kin >> 5;
  const int total = 16 * KS * 64;
  int tid = blockIdx.x * 256 + threadIdx.x;
  if (tid >= total) return;
  const int l = tid & 63;
  const int ks = (tid >> 6) % KS;
  const int nf = tid / (64 * KS);
  const float* src = W + (size_t)(nf * 16 + (l & 15)) * Kin + ks * 32 + (l >> 4) * 8;
  short8v v;
#pragma unroll
  for (int j = 0; j < 8; ++j) v[j] = f2bs(src[j]);
  *(short8v*)(P + (size_t)tid * 8) = v;
}

// ---------------- pack E (f32 [N][512]) into bf16 B-fragment order (EP) ---------------
// EP[((ns*32 + df)*64 + lane)*8 + j] = bf16( E[ns*32 + (lane>>4)*8 + j][df*16 + (lane&15)] )
__global__ __launch_bounds__(256) void packE_kernel(const float* __restrict__ E,
                                                    short* __restrict__ EP) {
  const size_t s = (size_t)blockIdx.x * 256 + threadIdx.x;
  const int lane = (int)(s & 63);
  const int df = (int)((s >> 6) & 31);
  const int ns = (int)(s >> 11);
  if (ns >= NSTEPS) return;
  const int lo = lane & 15, q = lane >> 4;
  const float* src = E + ((size_t)ns * 32 + q * 8) * DIM + df * 16 + lo;
  short8v v;
#pragma unroll
  for (int j = 0; j < 8; ++j) v[j] = f2bs(src[(size_t)j * DIM]);
  *(short8v*)(EP + s * 8) = v;
}

// ---------------- fused bf16-MFMA MLP + softmax + argmax + packed-gamma export --------
// 256 threads = 4 waves (wc = col quarter). Block owns 64 rows x 256 cols.
__global__ __launch_bounds__(256, 4) void mlp_mfma_kernel(
    const float* __restrict__ E,
    const short* __restrict__ PW1, const short* __restrict__ PW2,
    const short* __restrict__ PW3,
    const float* __restrict__ b1, const float* __restrict__ b2,
    const float* __restrict__ b3,
    short* __restrict__ gammaP, float* __restrict__ idx_out,
    float* __restrict__ gsp, int* __restrict__ tiecnt, int* __restrict__ tielist) {
  __shared__ __align__(16) short X[BM * 256];   // 32KB, XOR-swizzled bf16 activations
  __shared__ float redV[4][BM];
  __shared__ float redI[4][BM];
  __shared__ float red2[4][BM];
  __shared__ float rowM[BM];
  __shared__ float rowS[BM];
  __shared__ int lrows[BM];
  __shared__ int lcnt;
  __shared__ int gbase;

  const int t = threadIdx.x;
  const int blk = blockIdx.x;
  const int wc = t >> 6;
  const int lane = t & 63;
  const int lo = lane & 15;
  const int q = lane >> 4;

  if (t == 0) lcnt = 0;

  f32x4 acc[4][4];

  // ===== layer 1: acc = E @ W1^T =====
#pragma unroll
  for (int m = 0; m < 4; ++m)
#pragma unroll
    for (int n = 0; n < 4; ++n) acc[m][n] = (f32x4){0.f, 0.f, 0.f, 0.f};

  const float* e0 = E + (size_t)(blk * BM + lo) * DIM + q * 8;
#pragma unroll
  for (int ks = 0; ks < 16; ++ks) {
    short8v a[4];
#pragma unroll
    for (int m = 0; m < 4; ++m) {
      const float* ep = e0 + m * 16 * DIM + ks * 32;
      float4 x0 = *(const float4*)ep;
      float4 x1 = *(const float4*)(ep + 4);
      short8v av;
      av[0] = f2bs(x0.x); av[1] = f2bs(x0.y); av[2] = f2bs(x0.z); av[3] = f2bs(x0.w);
      av[4] = f2bs(x1.x); av[5] = f2bs(x1.y); av[6] = f2bs(x1.z); av[7] = f2bs(x1.w);
      a[m] = av;
    }
#pragma unroll
    for (int n = 0; n < 4; ++n) {
      short8v b = *(const short8v*)(PW1 + ((size_t)((wc * 4 + n) * 16 + ks) * 64 + lane) * 8);
#pragma unroll
      for (int m = 0; m < 4; ++m)
        acc[m][n] = __builtin_amdgcn_mfma_f32_16x16x32_bf16(a[m], b, acc[m][n], 0, 0, 0);
    }
  }
  {  // epilogue 1: bias + leaky -> X
    float bc[4];
#pragma unroll
    for (int n = 0; n < 4; ++n) bc[n] = b1[wc * 64 + n * 16 + lo];
#pragma unroll
    for (int m = 0; m < 4; ++m)
#pragma unroll
      for (int j = 0; j < 4; ++j) {
        const int row = m * 16 + 4 * q + j;
#pragma unroll
        for (int n = 0; n < 4; ++n) {
          float v = acc[m][n][j] + bc[n];
          v = v > 0.f ? v : 0.01f * v;
          const int col = wc * 64 + n * 16 + lo;
          X[row * 256 + ((((col >> 3) ^ (row & 7)) << 3) | (col & 7))] = f2bs(v);
        }
      }
  }
  __syncthreads();

  // ===== layer 2 =====
#pragma unroll
  for (int m = 0; m < 4; ++m)
#pragma unroll
    for (int n = 0; n < 4; ++n) acc[m][n] = (f32x4){0.f, 0.f, 0.f, 0.f};
#pragma unroll
  for (int ks = 0; ks < 8; ++ks) {
    short8v a[4];
#pragma unroll
    for (int m = 0; m < 4; ++m) {
      const int row = m * 16 + lo;
      const int ck = (ks * 4 + q) ^ (row & 7);
      a[m] = *(const short8v*)&X[row * 256 + ck * 8];
    }
#pragma unroll
    for (int n = 0; n < 4; ++n) {
      short8v b = *(const short8v*)(PW2 + ((size_t)((wc * 4 + n) * 8 + ks) * 64 + lane) * 8);
#pragma unroll
      for (int m = 0; m < 4; ++m)
        acc[m][n] = __builtin_amdgcn_mfma_f32_16x16x32_bf16(a[m], b, acc[m][n], 0, 0, 0);
    }
  }
  __syncthreads();
  {  // epilogue 2
    float bc[4];
#pragma unroll
    for (int n = 0; n < 4; ++n) bc[n] = b2[wc * 64 + n * 16 + lo];
#pragma unroll
    for (int m = 0; m < 4; ++m)
#pragma unroll
      for (int j = 0; j < 4; ++j) {
        const int row = m * 16 + 4 * q + j;
#pragma unroll
        for (int n = 0; n < 4; ++n) {
          float v = acc[m][n][j] + bc[n];
          v = v > 0.f ? v : 0.01f * v;
          const int col = wc * 64 + n * 16 + lo;
          X[row * 256 + ((((col >> 3) ^ (row & 7)) << 3) | (col & 7))] = f2bs(v);
        }
      }
  }
  __syncthreads();

  // ===== layer 3 =====
#pragma unroll
  for (int m = 0; m < 4; ++m)
#pragma unroll
    for (int n = 0; n < 4; ++n) acc[m][n] = (f32x4){0.f, 0.f, 0.f, 0.f};
#pragma unroll
  for (int ks = 0; ks < 8; ++ks) {
    short8v a[4];
#pragma unroll
    for (int m = 0; m < 4; ++m) {
      const int row = m * 16 + lo;
      const int ck = (ks * 4 + q) ^ (row & 7);
      a[m] = *(const short8v*)&X[row * 256 + ck * 8];
    }
#pragma unroll
    for (int n = 0; n < 4; ++n) {
      short8v b = *(const short8v*)(PW3 + ((size_t)((wc * 4 + n) * 8 + ks) * 64 + lane) * 8);
#pragma unroll
      for (int m = 0; m < 4; ++m)
        acc[m][n] = __builtin_amdgcn_mfma_f32_16x16x32_bf16(a[m], b, acc[m][n], 0, 0, 0);
    }
  }
  {  // + b3
    float bc[4];
#pragma unroll
    for (int n = 0; n < 4; ++n) bc[n] = b3[wc * 64 + n * 16 + lo];
#pragma unroll
    for (int m = 0; m < 4; ++m)
#pragma unroll
      for (int n = 0; n < 4; ++n)
#pragma unroll
        for (int j = 0; j < 4; ++j) acc[m][n][j] += bc[n];
  }

  // ===== phase A: per-row wave-slice top2 + argmax =====
#pragma unroll
  for (int m = 0; m < 4; ++m)
#pragma unroll
    for (int j = 0; j < 4; ++j) {
      const int r = m * 16 + 4 * q + j;
      float mx = acc[m][0][j];
      int mi = wc * 64 + lo;
      float m2 = -3.4e38f;
#pragma unroll
      for (int n = 1; n < 4; ++n) {
        float v = acc[m][n][j];
        int c = wc * 64 + n * 16 + lo;
        if (v > mx) { m2 = mx; mx = v; mi = c; }
        else if (v > m2) m2 = v;
      }
#pragma unroll
      for (int off = 1; off < 16; off <<= 1) {
        float ov = __shfl_xor(mx, off, 64);
        int oi = __shfl_xor(mi, off, 64);
        float o2 = __shfl_xor(m2, off, 64);
        float nm2 = fmaxf(m2, o2);
        if (ov > mx) { nm2 = fmaxf(nm2, mx); mx = ov; mi = oi; }
        else { nm2 = fmaxf(nm2, ov); if (ov == mx && oi < mi) mi = oi; }
        m2 = nm2;
      }
      if (lo == 0) { redV[wc][r] = mx; redI[wc][r] = __int_as_float(mi); red2[wc][r] = m2; }
    }
  __syncthreads();

  // ===== phase B: finalize per row, flag ties =====
  if (t < BM) {
    float gm = -3.4e38f, g2 = -3.4e38f;
    int gi = 0;
#pragma unroll
    for (int w = 0; w < 4; ++w) {
      float v = redV[w][t];
      int i2 = __float_as_int(redI[w][t]);
      float s2 = red2[w][t];
      if (v > gm) { g2 = fmaxf(fmaxf(g2, gm), s2); gm = v; gi = i2; }
      else { if (v == gm && i2 < gi) gi = i2; g2 = fmaxf(g2, v); }
    }
    rowM[t] = gm;
    idx_out[(size_t)blk * BM + t] = (float)gi;
    if (gm - g2 < MARGIN) { int p = atomicAdd(&lcnt, 1); lrows[p] = blk * BM + t; }
  }
  __syncthreads();

  // ===== phase C: exp + row sums =====
#pragma unroll
  for (int m = 0; m < 4; ++m)
#pragma unroll
    for (int j = 0; j < 4; ++j) {
      const int r = m * 16 + 4 * q + j;
      const float gm = rowM[r];
      float s = 0.f;
#pragma unroll
      for (int n = 0; n < 4; ++n) {
        float e = expf(acc[m][n][j] - gm);
        acc[m][n][j] = e;
        s += e;
      }
#pragma unroll
      for (int off = 1; off < 16; off <<= 1) s += __shfl_xor(s, off, 64);
      if (lo == 0) redV[wc][r] = s;
    }
  __syncthreads();
  if (t < BM) rowS[t] = redV[0][t] + redV[1][t] + redV[2][t] + redV[3][t];
  __syncthreads();

  // ===== phase D: gamma -> X (swizzled bf16), column partial sums =====
  float csum[4] = {0.f, 0.f, 0.f, 0.f};
#pragma unroll
  for (int m = 0; m < 4; ++m)
#pragma unroll
    for (int j = 0; j < 4; ++j) {
      const int r = m * 16 + 4 * q + j;
      const float inv = 1.0f / rowS[r];
#pragma unroll
      for (int n = 0; n < 4; ++n) {
        float g = acc[m][n][j] * inv;
        csum[n] += g;
        const int col = wc * 64 + n * 16 + lo;
        X[r * 256 + ((((col >> 3) ^ (r & 7)) << 3) | (col & 7))] = f2bs(g);
      }
    }
#pragma unroll
  for (int n = 0; n < 4; ++n) {
    csum[n] += __shfl_xor(csum[n], 16, 64);
    csum[n] += __shfl_xor(csum[n], 32, 64);
  }
  if (q == 0) {
#pragma unroll
    for (int n = 0; n < 4; ++n)
      gsp[(size_t)blk * KC + wc * 64 + n * 16 + lo] = csum[n];
  }
  __syncthreads();

  // ===== export gamma in packed A-frag order (gammaP) =====
#pragma unroll
  for (int ns = 0; ns < 2; ++ns)
#pragma unroll
    for (int i = 0; i < 4; ++i) {
      const int kf = wc * 4 + i;
      const int k = kf * 16 + lo;
      short8v v;
#pragma unroll
      for (int j = 0; j < 8; ++j) {
        const int r = ns * 32 + q * 8 + j;
        v[j] = X[r * 256 + ((((k >> 3) ^ (r & 7)) << 3) | (k & 7))];
      }
      *(short8v*)(gammaP + ((size_t)((blk * 2 + ns) * 16 + kf) * 64 + lane) * 8) = v;
    }

  // flush tie list
  if (t == 0 && lcnt > 0) gbase = atomicAdd(tiecnt, lcnt);
  __syncthreads();
  if (t < lcnt) tielist[gbase + t] = lrows[t];
}

// ---------------- exact f32 recompute of flagged rows (argmax only) -------------------
__global__ __launch_bounds__(256, 2) void recompute_kernel(
    const float* __restrict__ E,
    const float* __restrict__ W1T, const float* __restrict__ W2T,
    const float* __restrict__ W3T,
    const float* __restrict__ b1, const float* __restrict__ b2,
    const float* __restrict__ b3,
    const int* __restrict__ tiecnt, const int* __restrict__ tielist,
    float* __restrict__ idx_out) {
  __shared__ float Xa[32][KC];
  __shared__ float Xb[32][KC];
  __shared__ float Wt[8][KC];
  __shared__ float Et[8][32];
  __shared__ int rid[32];

  const int t = threadIdx.x;
  const int cg = t & 31;
  const int rg = t >> 5;
  const int cnt = *tiecnt;

  for (int base = blockIdx.x * 32; base < cnt; base += gridDim.x * 32) {
    const int nr = min(32, cnt - base);
    if (t < 32) rid[t] = tielist[base + min(t, nr - 1)];
    __syncthreads();

    float acc[4][2][4];
#pragma unroll
    for (int i = 0; i < 4; ++i)
#pragma unroll
      for (int j = 0; j < 2; ++j)
#pragma unroll
        for (int c = 0; c < 4; ++c) acc[i][j][c] = 0.0f;
    for (int d0 = 0; d0 < DIM; d0 += 8) {
      const float4* wsrc = (const float4*)(W1T + (size_t)d0 * KC);
      float4* wdst = (float4*)(&Wt[0][0]);
      wdst[t] = wsrc[t];
      wdst[t + 256] = wsrc[t + 256];
      Et[t & 7][t >> 3] = E[(size_t)rid[t >> 3] * DIM + d0 + (t & 7)];
      __syncthreads();
#pragma unroll
      for (int dd = 0; dd < 8; ++dd) {
        float4 e4 = *(const float4*)(&Et[dd][rg * 4]);
        float4 w0 = *(const float4*)(&Wt[dd][cg * 4]);
        float4 w1 = *(const float4*)(&Wt[dd][cg * 4 + 128]);
        float ev[4] = {e4.x, e4.y, e4.z, e4.w};
        float wv[2][4] = {{w0.x, w0.y, w0.z, w0.w}, {w1.x, w1.y, w1.z, w1.w}};
#pragma unroll
        for (int i = 0; i < 4; ++i)
#pragma unroll
          for (int j = 0; j < 2; ++j)
#pragma unroll
            for (int c = 0; c < 4; ++c)
              acc[i][j][c] = fmaf(ev[i], wv[j][c], acc[i][j][c]);
      }
      __syncthreads();
    }
    {
      float4 bb0 = *(const float4*)(b1 + cg * 4);
      float4 bb1 = *(const float4*)(b1 + cg * 4 + 128);
      float bv[2][4] = {{bb0.x, bb0.y, bb0.z, bb0.w}, {bb1.x, bb1.y, bb1.z, bb1.w}};
#pragma unroll
      for (int i = 0; i < 4; ++i)
#pragma unroll
        for (int j = 0; j < 2; ++j) {
          float4 v;
          float vv[4];
#pragma unroll
          for (int c = 0; c < 4; ++c) {
            float x = acc[i][j][c] + bv[j][c];
            vv[c] = x > 0.0f ? x : 0.01f * x;
          }
          v.x = vv[0]; v.y = vv[1]; v.z = vv[2]; v.w = vv[3];
          *(float4*)(&Xa[rg * 4 + i][cg * 4 + j * 128]) = v;
        }
    }
    __syncthreads();
#pragma unroll
    for (int i = 0; i < 4; ++i)
#pragma unroll
      for (int j = 0; j < 2; ++j)
#pragma unroll
        for (int c = 0; c < 4; ++c) acc[i][j][c] = 0.0f;
    for (int d0 = 0; d0 < KC; d0 += 8) {
      const float4* wsrc = (const float4*)(W2T + (size_t)d0 * KC);
      float4* wdst = (float4*)(&Wt[0][0]);
      wdst[t] = wsrc[t];
      wdst[t + 256] = wsrc[t + 256];
      __syncthreads();
#pragma unroll
      for (int dd = 0; dd < 8; ++dd) {
        const int d = d0 + dd;
        float ev[4];
#pragma unroll
        for (int i = 0; i < 4; ++i) ev[i] = Xa[rg * 4 + i][d];
        float4 w0 = *(const float4*)(&Wt[dd][cg * 4]);
        float4 w1 = *(const float4*)(&Wt[dd][cg * 4 + 128]);
        float wv[2][4] = {{w0.x, w0.y, w0.z, w0.w}, {w1.x, w1.y, w1.z, w1.w}};
#pragma unroll
        for (int i = 0; i < 4; ++i)
#pragma unroll
          for (int j = 0; j < 2; ++j)
#pragma unroll
            for (int c = 0; c < 4; ++c)
              acc[i][j][c] = fmaf(ev[i], wv[j][c], acc[i][j][c]);
      }
      __syncthreads();
    }
    {
      float4 bb0 = *(const float4*)(b2 + cg * 4);
      float4 bb1 = *(const float4*)(b2 + cg * 4 + 128);
      float bv[2][4] = {{bb0.x, bb0.y, bb0.z, bb0.w}, {bb1.x, bb1.y, bb1.z, bb1.w}};
#pragma unroll
      for (int i = 0; i < 4; ++i)
#pragma unroll
        for (int j = 0; j < 2; ++j) {
          float4 v;
          float vv[4];
#pragma unroll
          for (int c = 0; c < 4; ++c) {
            float x = acc[i][j][c] + bv[j][c];
            vv[c] = x > 0.0f ? x : 0.01f * x;
          }
          v.x = vv[0]; v.y = vv[1]; v.z = vv[2]; v.w = vv[3];
          *(float4*)(&Xb[rg * 4 + i][cg * 4 + j * 128]) = v;
        }
    }
    __syncthreads();
#pragma unroll
    for (int i = 0; i < 4; ++i)
#pragma unroll
      for (int j = 0; j < 2; ++j)
#pragma unroll
        for (int c = 0; c < 4; ++c) acc[i][j][c] = 0.0f;
    for (int d0 = 0; d0 < KC; d0 += 8) {
      const float4* wsrc = (const float4*)(W3T + (size_t)d0 * KC);
      float4* wdst = (float4*)(&Wt[0][0]);
      wdst[t] = wsrc[t];
      wdst[t + 256] = wsrc[t + 256];
      __syncthreads();
#pragma unroll
      for (int dd = 0; dd < 8; ++dd) {
        const int d = d0 + dd;
        float ev[4];
#pragma unroll
        for (int i = 0; i < 4; ++i) ev[i] = Xb[rg * 4 + i][d];
        float4 w0 = *(const float4*)(&Wt[dd][cg * 4]);
        float4 w1 = *(const float4*)(&Wt[dd][cg * 4 + 128]);
        float wv[2][4] = {{w0.x, w0.y, w0.z, w0.w}, {w1.x, w1.y, w1.z, w1.w}};
#pragma unroll
        for (int i = 0; i < 4; ++i)
#pragma unroll
          for (int j = 0; j < 2; ++j)
#pragma unroll
            for (int c = 0; c < 4; ++c)
              acc[i][j][c] = fmaf(ev[i], wv[j][c], acc[i][j][c]);
      }
      __syncthreads();
    }
    {
      float4 bb0 = *(const float4*)(b3 + cg * 4);
      float4 bb1 = *(const float4*)(b3 + cg * 4 + 128);
      float bv[2][4] = {{bb0.x, bb0.y, bb0.z, bb0.w}, {bb1.x, bb1.y, bb1.z, bb1.w}};
#pragma unroll
      for (int i = 0; i < 4; ++i)
#pragma unroll
        for (int j = 0; j < 2; ++j) {
          float4 v;
          v.x = acc[i][j][0] + bv[j][0];
          v.y = acc[i][j][1] + bv[j][1];
          v.z = acc[i][j][2] + bv[j][2];
          v.w = acc[i][j][3] + bv[j][3];
          *(float4*)(&Xa[rg * 4 + i][cg * 4 + j * 128]) = v;
        }
    }
    __syncthreads();
    const int wv_ = t >> 6;
    const int lane = t & 63;
#pragma unroll 1
    for (int rr = 0; rr < 8; ++rr) {
      const int lr = wv_ * 8 + rr;
      float4 x4 = *(const float4*)(&Xa[lr][lane * 4]);
      float xv[4] = {x4.x, x4.y, x4.z, x4.w};
      float bvv = xv[0];
      int bi = lane * 4;
#pragma unroll
      for (int c = 1; c < 4; ++c)
        if (xv[c] > bvv) { bvv = xv[c]; bi = lane * 4 + c; }
#pragma unroll
      for (int off = 32; off > 0; off >>= 1) {
        float ov = __shfl_xor(bvv, off, 64);
        int oi = __shfl_xor(bi, off, 64);
        if (ov > bvv || (ov == bvv && oi < bi)) { bvv = ov; bi = oi; }
      }
      if (lane == 0 && lr < nr) idx_out[rid[lr]] = (float)bi;
    }
    __syncthreads();
  }
}

// ---------------- gamma_sum reduce: gsp[3125][256] -> gsum[256] ----------------
__global__ __launch_bounds__(256) void gsum_reduce_kernel(const float* __restrict__ gsp,
                                                          float* __restrict__ gsum) {
  const int b = blockIdx.x;   // 0..24
  const int k = threadIdx.x;
  float s = 0.0f;
  for (int i = 0; i < 125; ++i) s += gsp[(size_t)(b * 125 + i) * KC + k];
  atomicAdd(&gsum[k], s);
}

// ---------------- KL over packed gamma (gammaP) ----------------
// Block = 4 waves; each wave handles 2 n-steps (32 rows each).
__global__ __launch_bounds__(256) void kl_kernel(const short* __restrict__ gP,
                                                 const float* __restrict__ gsum,
                                                 float* __restrict__ out_kl) {
  const int t = threadIdx.x;
  const int w = t >> 6, lane = t & 63;
  const int lo = lane & 15;
  __shared__ float bsum[4];
  float kacc = 0.f;
#pragma unroll 1
  for (int it = 0; it < 2; ++it) {
    const int ns = blockIdx.x * 8 + w * 2 + it;
    if (ns < NSTEPS) {
      float s12[8], m[8], s[8];
#pragma unroll
      for (int j = 0; j < 8; ++j) { s12[j] = 0.f; m[j] = 0.f; s[j] = 0.f; }
#pragma unroll 1
      for (int kf = 0; kf < 16; ++kf) {
        short8v g8 = *(const short8v*)(gP + ((size_t)(ns * 16 + kf) * 64 + lane) * 8);
        const float rg = 1.0f / gsum[kf * 16 + lo];
#pragma unroll
        for (int j = 0; j < 8; ++j) {
          float g = bs2f(g8[j]);
          float y = g * g * rg;
          s12[j] += (g > 0.f ? g * __logf(g) : 0.f) - g * y;
          float nm = fmaxf(m[j], y);
          s[j] = s[j] * __expf(m[j] - nm) + __expf(y - nm);
          m[j] = nm;
        }
      }
#pragma unroll
      for (int off = 1; off < 16; off <<= 1) {
#pragma unroll
        for (int j = 0; j < 8; ++j) {
          float om = __shfl_xor(m[j], off, 64);
          float os = __shfl_xor(s[j], off, 64);
          float nm = fmaxf(m[j], om);
          s[j] = s[j] * __expf(m[j] - nm) + os * __expf(om - nm);
          m[j] = nm;
          s12[j] += __shfl_xor(s12[j], off, 64);
        }
      }
      if (lo == 0) {
#pragma unroll
        for (int j = 0; j < 8; ++j) kacc += s12[j] + m[j] + __logf(s[j]);
      }
    }
  }
#pragma unroll
  for (int off = 1; off < 64; off <<= 1) kacc += __shfl_xor(kacc, off, 64);
  if (lane == 0) bsum[w] = kacc;
  __syncthreads();
  if (t == 0) atomicAdd(out_kl, bsum[0] + bsum[1] + bsum[2] + bsum[3]);
}

// ---------------- mean GEMM: partial[c] += gammaP^T-block @ EP-block (MFMA) -----------
// grid.x = 8 (kt 0..3 x dt 0..1), grid.y = MCHUNKS. Wave w owns d-range dt*256 + w*64.
__global__ __launch_bounds__(256, 4) void mean_mfma(const short* __restrict__ gP,
                                                    const short* __restrict__ EP,
                                                    float* __restrict__ partial) {
  const int t = threadIdx.x;
  const int w = t >> 6, lane = t & 63;
  const int kt = blockIdx.x >> 1;
  const int dt = blockIdx.x & 1;
  const int c = blockIdx.y;
  f32x4 acc[4][4];
#pragma unroll
  for (int i = 0; i < 4; ++i)
#pragma unroll
    for (int j = 0; j < 4; ++j) acc[i][j] = (f32x4){0.f, 0.f, 0.f, 0.f};

  const int ns0 = c * MSTEPS;
#pragma unroll 2
  for (int nsi = 0; nsi < MSTEPS; ++nsi) {
    const int ns = ns0 + nsi;
    short8v af[4], bf[4];
#pragma unroll
    for (int i = 0; i < 4; ++i)
      af[i] = *(const short8v*)(gP + ((size_t)(ns * 16 + kt * 4 + i) * 64 + lane) * 8);
#pragma unroll
    for (int j = 0; j < 4; ++j)
      bf[j] = *(const short8v*)(EP + ((size_t)(ns * 32 + dt * 16 + w * 4 + j) * 64 + lane) * 8);
#pragma unroll
    for (int i = 0; i < 4; ++i)
#pragma unroll
      for (int j = 0; j < 4; ++j)
        acc[i][j] = __builtin_amdgcn_mfma_f32_16x16x32_bf16(af[i], bf[j], acc[i][j], 0, 0, 0);
  }
  const int lo = lane & 15, q = lane >> 4;
  const size_t pbase = (size_t)c * (KC * DIM);
#pragma unroll
  for (int i = 0; i < 4; ++i)
#pragma unroll
    for (int j = 0; j < 4; ++j) {
      const int d = dt * 256 + w * 64 + j * 16 + lo;
#pragma unroll
      for (int r = 0; r < 4; ++r) {
        const int k = kt * 64 + i * 16 + q * 4 + r;
        partial[pbase + (size_t)k * DIM + d] = acc[i][j][r];
      }
    }
}

// ---------------- mean pass 2: reduce chunks, divide by gamma_sum ----------------
__global__ __launch_bounds__(256) void mean_pass2(const float* __restrict__ partial,
                                                  const float* __restrict__ gsum,
                                                  float* __restrict__ out_mean) {
  const int t = blockIdx.x * 256 + threadIdx.x;
  float s = 0.0f;
  for (int c = 0; c < MCHUNKS; ++c) s += partial[(size_t)c * (KC * DIM) + t];
  out_mean[t] = s / gsum[t >> 9];
}

extern "C" void kernel_launch(void* const* d_in, const int* in_sizes, int n_in,
                              void* d_out, int out_size, void* d_ws, size_t ws_size,
                              hipStream_t stream) {
  const float* E  = (const float*)d_in[0];
  const float* W1 = (const float*)d_in[1];
  const float* b1 = (const float*)d_in[2];
  const float* W2 = (const float*)d_in[3];
  const float* b2 = (const float*)d_in[4];
  const float* W3 = (const float*)d_in[5];
  const float* b3 = (const float*)d_in[6];
  float* out = (float*)d_out;  // [0]=kl, [1..N]=indices(float), [1+N..]=mean[K][D]

  char* p = (char*)d_ws;
  short* gammaP = (short*)p; p += (size_t)NROWS * KC * 2;            // 102.4 MB
  short* EPb    = (short*)p; p += (size_t)NROWS * DIM * 2;           // 204.8 MB
  float* gsp    = (float*)p; p += (size_t)NBLK_MLP * KC * 4;         // 3.2 MB
  float* gsum   = (float*)p; p += KC * 4;
  short* pw1    = (short*)p; p += (size_t)KC * DIM * 2;
  short* pw2    = (short*)p; p += (size_t)KC * KC * 2;
  short* pw3    = (short*)p; p += (size_t)KC * KC * 2;
  float* w1t    = (float*)p; p += (size_t)DIM * KC * 4;
  float* w2t    = (float*)p; p += (size_t)KC * KC * 4;
  float* w3t    = (float*)p; p += (size_t)KC * KC * 4;
  int* tcnt     = (int*)p;   p += 256;
  int* tlist    = (int*)p;   p += (size_t)NROWS * 4;                 // 0.8 MB
  float* mpart  = (float*)p; p += (size_t)MCHUNKS * KC * DIM * 4;    // 67.1 MB

  hipMemsetAsync(d_out, 0, sizeof(float), stream);
  hipMemsetAsync(gsum, 0, KC * sizeof(float), stream);
  hipMemsetAsync(tcnt, 0, sizeof(int), stream);

  packW_kernel<<<64, 256, 0, stream>>>(W1, pw1, DIM);
  packW_kernel<<<32, 256, 0, stream>>>(W2, pw2, KC);
  packW_kernel<<<32, 256, 0, stream>>>(W3, pw3, KC);
  transpose_kernel<<<dim3(DIM / 32, KC / 32), dim3(32, 8), 0, stream>>>(W1, w1t, KC, DIM);
  transpose_kernel<<<dim3(KC / 32, KC / 32), dim3(32, 8), 0, stream>>>(W2, w2t, KC, KC);
  transpose_kernel<<<dim3(KC / 32, KC / 32), dim3(32, 8), 0, stream>>>(W3, w3t, KC, KC);
  packE_kernel<<<50000, 256, 0, stream>>>(E, EPb);

  mlp_mfma_kernel<<<NBLK_MLP, 256, 0, stream>>>(E, pw1, pw2, pw3, b1, b2, b3,
                                                gammaP, out + 1, gsp, tcnt, tlist);
  recompute_kernel<<<960, 256, 0, stream>>>(E, w1t, w2t, w3t, b1, b2, b3,
                                            tcnt, tlist, out + 1);
  gsum_reduce_kernel<<<25, 256, 0, stream>>>(gsp, gsum);
  kl_kernel<<<(NSTEPS + 7) / 8, 256, 0, stream>>>(gammaP, gsum, out);
  mean_mfma<<<dim3(8, MCHUNKS), 256, 0, stream>>>(gammaP, EPb, mpart);
  mean_pass2<<<(KC * DIM) / 256, 256, 0, stream>>>(mpart, gsum, out + 1 + NROWS);
}

// Round 4
// 1605.077 us; speedup vs baseline: 1.7660x; 1.2455x over previous
//
#include <hip/hip_runtime.h>
#include <math.h>

#define NROWS 200000
#define DIM   512
#define KC    256
#define BM    64
#define NBLK_MLP (NROWS / BM)      // 3125
#define NSTEPS   (NROWS / 32)      // 6250
#define MCHUNKS  125
#define MSTEPS   (NSTEPS / MCHUNKS) // 50
#define MARGIN   0.0625f

typedef float f32x4 __attribute__((ext_vector_type(4)));
typedef short short8v __attribute__((ext_vector_type(8)));
typedef short short4v __attribute__((ext_vector_type(4)));

__device__ inline short f2bs(float f) {            // f32 -> bf16 bits (RNE)
  unsigned u = __float_as_uint(f);
  unsigned r = (u + 0x7FFFu + ((u >> 16) & 1u)) >> 16;
  return (short)r;
}
__device__ inline float bs2f(short s) {            // bf16 bits -> f32 (exact)
  return __uint_as_float(((unsigned)(unsigned short)s) << 16);
}

// ---------------- pack W (f32 [256][Kin]) into bf16 B-fragment order, hi + lo ---------
// P[((nf*KS + ks)*64 + lane)*8 + j] = bf16( W[nf*16 + (lane&15)][ks*32 + (lane>>4)*8 + j] )
__global__ __launch_bounds__(256) void packW_kernel(const float* __restrict__ W,
                                                    short* __restrict__ Ph,
                                                    short* __restrict__ Pl, int Kin) {
  const int KS = Kin >> 5;
  const int total = 16 * KS * 64;
  int tid = blockIdx.x * 256 + threadIdx.x;
  if (tid >= total) return;
  const int l = tid & 63;
  const int ks = (tid >> 6) % KS;
  const int nf = tid / (64 * KS);
  const float* src = W + (size_t)(nf * 16 + (l & 15)) * Kin + ks * 32 + (l >> 4) * 8;
  short8v vh, vl;
#pragma unroll
  for (int j = 0; j < 8; ++j) {
    float x = src[j];
    short h = f2bs(x);
    vh[j] = h;
    vl[j] = f2bs(x - bs2f(h));
  }
  *(short8v*)(Ph + (size_t)tid * 8) = vh;
  *(short8v*)(Pl + (size_t)tid * 8) = vl;
}

// ---------------- pack E (f32 [N][512]) into bf16 B-fragment order (EP) ---------------
// EP[((ns*32 + df)*64 + lane)*8 + j] = bf16( E[ns*32 + (lane>>4)*8 + j][df*16 + (lane&15)] )
__global__ __launch_bounds__(256) void packE_kernel(const float* __restrict__ E,
                                                    short* __restrict__ EP) {
  const size_t s = (size_t)blockIdx.x * 256 + threadIdx.x;
  const int lane = (int)(s & 63);
  const int df = (int)((s >> 6) & 31);
  const int ns = (int)(s >> 11);
  if (ns >= NSTEPS) return;
  const int lo = lane & 15, q = lane >> 4;
  const float* src = E + ((size_t)ns * 32 + q * 8) * DIM + df * 16 + lo;
  short8v v;
#pragma unroll
  for (int j = 0; j < 8; ++j) v[j] = f2bs(src[(size_t)j * DIM]);
  *(short8v*)(EP + s * 8) = v;
}

// ---------------- fused bf16-MFMA MLP + softmax + argmax + packed-gamma export --------
// 256 threads = 4 waves (wc = col quarter). Block owns 64 rows x 256 cols.
__global__ __launch_bounds__(256, 4) void mlp_mfma_kernel(
    const float* __restrict__ E,
    const short* __restrict__ PW1, const short* __restrict__ PW2,
    const short* __restrict__ PW3,
    const float* __restrict__ b1, const float* __restrict__ b2,
    const float* __restrict__ b3,
    short* __restrict__ gammaP, float* __restrict__ idx_out,
    float* __restrict__ gsp, int* __restrict__ tiecnt, int* __restrict__ tielist) {
  __shared__ __align__(16) short X[BM * 256];   // 32KB, XOR-swizzled bf16 activations
  __shared__ float redV[4][BM];
  __shared__ float redI[4][BM];
  __shared__ float red2[4][BM];
  __shared__ float rowM[BM];
  __shared__ float rowS[BM];
  __shared__ int lrows[BM];
  __shared__ int lcnt;
  __shared__ int gbase;

  const int t = threadIdx.x;
  const int blk = blockIdx.x;
  const int wc = t >> 6;
  const int lane = t & 63;
  const int lo = lane & 15;
  const int q = lane >> 4;

  if (t == 0) lcnt = 0;

  f32x4 acc[4][4];

  // ===== layer 1: acc = E @ W1^T =====
#pragma unroll
  for (int m = 0; m < 4; ++m)
#pragma unroll
    for (int n = 0; n < 4; ++n) acc[m][n] = (f32x4){0.f, 0.f, 0.f, 0.f};

  const float* e0 = E + (size_t)(blk * BM + lo) * DIM + q * 8;
#pragma unroll
  for (int ks = 0; ks < 16; ++ks) {
    short8v a[4];
#pragma unroll
    for (int m = 0; m < 4; ++m) {
      const float* ep = e0 + m * 16 * DIM + ks * 32;
      float4 x0 = *(const float4*)ep;
      float4 x1 = *(const float4*)(ep + 4);
      short8v av;
      av[0] = f2bs(x0.x); av[1] = f2bs(x0.y); av[2] = f2bs(x0.z); av[3] = f2bs(x0.w);
      av[4] = f2bs(x1.x); av[5] = f2bs(x1.y); av[6] = f2bs(x1.z); av[7] = f2bs(x1.w);
      a[m] = av;
    }
#pragma unroll
    for (int n = 0; n < 4; ++n) {
      short8v b = *(const short8v*)(PW1 + ((size_t)((wc * 4 + n) * 16 + ks) * 64 + lane) * 8);
#pragma unroll
      for (int m = 0; m < 4; ++m)
        acc[m][n] = __builtin_amdgcn_mfma_f32_16x16x32_bf16(a[m], b, acc[m][n], 0, 0, 0);
    }
  }
  {  // epilogue 1: bias + leaky -> X
    float bc[4];
#pragma unroll
    for (int n = 0; n < 4; ++n) bc[n] = b1[wc * 64 + n * 16 + lo];
#pragma unroll
    for (int m = 0; m < 4; ++m)
#pragma unroll
      for (int j = 0; j < 4; ++j) {
        const int row = m * 16 + 4 * q + j;
#pragma unroll
        for (int n = 0; n < 4; ++n) {
          float v = acc[m][n][j] + bc[n];
          v = v > 0.f ? v : 0.01f * v;
          const int col = wc * 64 + n * 16 + lo;
          X[row * 256 + ((((col >> 3) ^ (row & 7)) << 3) | (col & 7))] = f2bs(v);
        }
      }
  }
  __syncthreads();

  // ===== layer 2 =====
#pragma unroll
  for (int m = 0; m < 4; ++m)
#pragma unroll
    for (int n = 0; n < 4; ++n) acc[m][n] = (f32x4){0.f, 0.f, 0.f, 0.f};
#pragma unroll
  for (int ks = 0; ks < 8; ++ks) {
    short8v a[4];
#pragma unroll
    for (int m = 0; m < 4; ++m) {
      const int row = m * 16 + lo;
      const int ck = (ks * 4 + q) ^ (row & 7);
      a[m] = *(const short8v*)&X[row * 256 + ck * 8];
    }
#pragma unroll
    for (int n = 0; n < 4; ++n) {
      short8v b = *(const short8v*)(PW2 + ((size_t)((wc * 4 + n) * 8 + ks) * 64 + lane) * 8);
#pragma unroll
      for (int m = 0; m < 4; ++m)
        acc[m][n] = __builtin_amdgcn_mfma_f32_16x16x32_bf16(a[m], b, acc[m][n], 0, 0, 0);
    }
  }
  __syncthreads();
  {  // epilogue 2
    float bc[4];
#pragma unroll
    for (int n = 0; n < 4; ++n) bc[n] = b2[wc * 64 + n * 16 + lo];
#pragma unroll
    for (int m = 0; m < 4; ++m)
#pragma unroll
      for (int j = 0; j < 4; ++j) {
        const int row = m * 16 + 4 * q + j;
#pragma unroll
        for (int n = 0; n < 4; ++n) {
          float v = acc[m][n][j] + bc[n];
          v = v > 0.f ? v : 0.01f * v;
          const int col = wc * 64 + n * 16 + lo;
          X[row * 256 + ((((col >> 3) ^ (row & 7)) << 3) | (col & 7))] = f2bs(v);
        }
      }
  }
  __syncthreads();

  // ===== layer 3 =====
#pragma unroll
  for (int m = 0; m < 4; ++m)
#pragma unroll
    for (int n = 0; n < 4; ++n) acc[m][n] = (f32x4){0.f, 0.f, 0.f, 0.f};
#pragma unroll
  for (int ks = 0; ks < 8; ++ks) {
    short8v a[4];
#pragma unroll
    for (int m = 0; m < 4; ++m) {
      const int row = m * 16 + lo;
      const int ck = (ks * 4 + q) ^ (row & 7);
      a[m] = *(const short8v*)&X[row * 256 + ck * 8];
    }
#pragma unroll
    for (int n = 0; n < 4; ++n) {
      short8v b = *(const short8v*)(PW3 + ((size_t)((wc * 4 + n) * 8 + ks) * 64 + lane) * 8);
#pragma unroll
      for (int m = 0; m < 4; ++m)
        acc[m][n] = __builtin_amdgcn_mfma_f32_16x16x32_bf16(a[m], b, acc[m][n], 0, 0, 0);
    }
  }
  {  // + b3
    float bc[4];
#pragma unroll
    for (int n = 0; n < 4; ++n) bc[n] = b3[wc * 64 + n * 16 + lo];
#pragma unroll
    for (int m = 0; m < 4; ++m)
#pragma unroll
      for (int n = 0; n < 4; ++n)
#pragma unroll
        for (int j = 0; j < 4; ++j) acc[m][n][j] += bc[n];
  }

  // ===== phase A: per-row wave-slice top2 + argmax =====
#pragma unroll
  for (int m = 0; m < 4; ++m)
#pragma unroll
    for (int j = 0; j < 4; ++j) {
      const int r = m * 16 + 4 * q + j;
      float mx = acc[m][0][j];
      int mi = wc * 64 + lo;
      float m2 = -3.4e38f;
#pragma unroll
      for (int n = 1; n < 4; ++n) {
        float v = acc[m][n][j];
        int c = wc * 64 + n * 16 + lo;
        if (v > mx) { m2 = mx; mx = v; mi = c; }
        else if (v > m2) m2 = v;
      }
#pragma unroll
      for (int off = 1; off < 16; off <<= 1) {
        float ov = __shfl_xor(mx, off, 64);
        int oi = __shfl_xor(mi, off, 64);
        float o2 = __shfl_xor(m2, off, 64);
        float nm2 = fmaxf(m2, o2);
        if (ov > mx) { nm2 = fmaxf(nm2, mx); mx = ov; mi = oi; }
        else { nm2 = fmaxf(nm2, ov); if (ov == mx && oi < mi) mi = oi; }
        m2 = nm2;
      }
      if (lo == 0) { redV[wc][r] = mx; redI[wc][r] = __int_as_float(mi); red2[wc][r] = m2; }
    }
  __syncthreads();

  // ===== phase B: finalize per row, flag ties =====
  if (t < BM) {
    float gm = -3.4e38f, g2 = -3.4e38f;
    int gi = 0;
#pragma unroll
    for (int w = 0; w < 4; ++w) {
      float v = redV[w][t];
      int i2 = __float_as_int(redI[w][t]);
      float s2 = red2[w][t];
      if (v > gm) { g2 = fmaxf(fmaxf(g2, gm), s2); gm = v; gi = i2; }
      else { if (v == gm && i2 < gi) gi = i2; g2 = fmaxf(g2, v); }
    }
    rowM[t] = gm;
    idx_out[(size_t)blk * BM + t] = (float)gi;
    if (gm - g2 < MARGIN) { int p = atomicAdd(&lcnt, 1); lrows[p] = blk * BM + t; }
  }
  __syncthreads();

  // ===== phase C: exp + row sums =====
#pragma unroll
  for (int m = 0; m < 4; ++m)
#pragma unroll
    for (int j = 0; j < 4; ++j) {
      const int r = m * 16 + 4 * q + j;
      const float gm = rowM[r];
      float s = 0.f;
#pragma unroll
      for (int n = 0; n < 4; ++n) {
        float e = expf(acc[m][n][j] - gm);
        acc[m][n][j] = e;
        s += e;
      }
#pragma unroll
      for (int off = 1; off < 16; off <<= 1) s += __shfl_xor(s, off, 64);
      if (lo == 0) redV[wc][r] = s;
    }
  __syncthreads();
  if (t < BM) rowS[t] = redV[0][t] + redV[1][t] + redV[2][t] + redV[3][t];
  __syncthreads();

  // ===== phase D: gamma -> X (swizzled bf16), column partial sums =====
  float csum[4] = {0.f, 0.f, 0.f, 0.f};
#pragma unroll
  for (int m = 0; m < 4; ++m)
#pragma unroll
    for (int j = 0; j < 4; ++j) {
      const int r = m * 16 + 4 * q + j;
      const float inv = 1.0f / rowS[r];
#pragma unroll
      for (int n = 0; n < 4; ++n) {
        float g = acc[m][n][j] * inv;
        csum[n] += g;
        const int col = wc * 64 + n * 16 + lo;
        X[r * 256 + ((((col >> 3) ^ (r & 7)) << 3) | (col & 7))] = f2bs(g);
      }
    }
#pragma unroll
  for (int n = 0; n < 4; ++n) {
    csum[n] += __shfl_xor(csum[n], 16, 64);
    csum[n] += __shfl_xor(csum[n], 32, 64);
  }
  if (q == 0) {
#pragma unroll
    for (int n = 0; n < 4; ++n)
      gsp[(size_t)blk * KC + wc * 64 + n * 16 + lo] = csum[n];
  }
  __syncthreads();

  // ===== export gamma in packed A-frag order (gammaP) =====
#pragma unroll
  for (int ns = 0; ns < 2; ++ns)
#pragma unroll
    for (int i = 0; i < 4; ++i) {
      const int kf = wc * 4 + i;
      const int k = kf * 16 + lo;
      short8v v;
#pragma unroll
      for (int j = 0; j < 8; ++j) {
        const int r = ns * 32 + q * 8 + j;
        v[j] = X[r * 256 + ((((k >> 3) ^ (r & 7)) << 3) | (k & 7))];
      }
      *(short8v*)(gammaP + ((size_t)((blk * 2 + ns) * 16 + kf) * 64 + lane) * 8) = v;
    }

  // flush tie list
  if (t == 0 && lcnt > 0) gbase = atomicAdd(tiecnt, lcnt);
  __syncthreads();
  if (t < lcnt) tielist[gbase + t] = lrows[t];
}

// ---------------- split-bf16 MFMA recompute of flagged rows (argmax only) -------------
// value = hi + lo (two bf16); product via Ah*Bh + Ah*Bl + Al*Bh (f32 accum) ~ f32-exact.
__global__ __launch_bounds__(256, 2) void recompute_mfma_kernel(
    const float* __restrict__ E,
    const short* __restrict__ PW1h, const short* __restrict__ PW1l,
    const short* __restrict__ PW2h, const short* __restrict__ PW2l,
    const short* __restrict__ PW3h, const short* __restrict__ PW3l,
    const float* __restrict__ b1, const float* __restrict__ b2,
    const float* __restrict__ b3,
    const int* __restrict__ tiecnt, const int* __restrict__ tielist,
    float* __restrict__ idx_out) {
  __shared__ __align__(16) short Xh[BM * 256];   // 32KB hi
  __shared__ __align__(16) short Xl[BM * 256];   // 32KB lo
  __shared__ float redV[4][BM];
  __shared__ float redI[4][BM];
  __shared__ int rid[BM];

  const int t = threadIdx.x;
  const int wc = t >> 6;
  const int lane = t & 63;
  const int lo = lane & 15;
  const int q = lane >> 4;
  const int cnt = *tiecnt;

  for (int base = blockIdx.x * BM; base < cnt; base += gridDim.x * BM) {
    if (t < BM) rid[t] = tielist[min(base + t, cnt - 1)];
    __syncthreads();

    int rr0[4];
#pragma unroll
    for (int m = 0; m < 4; ++m) rr0[m] = rid[m * 16 + lo];

    f32x4 acc[4][4];
    // ===== layer 1 =====
#pragma unroll
    for (int m = 0; m < 4; ++m)
#pragma unroll
      for (int n = 0; n < 4; ++n) acc[m][n] = (f32x4){0.f, 0.f, 0.f, 0.f};
#pragma unroll 2
    for (int ks = 0; ks < 16; ++ks) {
      short8v ah[4], al[4];
#pragma unroll
      for (int m = 0; m < 4; ++m) {
        const float* ep = E + (size_t)rr0[m] * DIM + ks * 32 + q * 8;
        float4 x0 = *(const float4*)ep;
        float4 x1 = *(const float4*)(ep + 4);
        float xv[8] = {x0.x, x0.y, x0.z, x0.w, x1.x, x1.y, x1.z, x1.w};
        short8v vh, vl;
#pragma unroll
        for (int j = 0; j < 8; ++j) {
          short h = f2bs(xv[j]);
          vh[j] = h;
          vl[j] = f2bs(xv[j] - bs2f(h));
        }
        ah[m] = vh; al[m] = vl;
      }
#pragma unroll
      for (int n = 0; n < 4; ++n) {
        const size_t off = ((size_t)((wc * 4 + n) * 16 + ks) * 64 + lane) * 8;
        short8v bh = *(const short8v*)(PW1h + off);
        short8v bl = *(const short8v*)(PW1l + off);
#pragma unroll
        for (int m = 0; m < 4; ++m) {
          acc[m][n] = __builtin_amdgcn_mfma_f32_16x16x32_bf16(ah[m], bh, acc[m][n], 0, 0, 0);
          acc[m][n] = __builtin_amdgcn_mfma_f32_16x16x32_bf16(ah[m], bl, acc[m][n], 0, 0, 0);
          acc[m][n] = __builtin_amdgcn_mfma_f32_16x16x32_bf16(al[m], bh, acc[m][n], 0, 0, 0);
        }
      }
    }
    {  // epilogue 1: bias + leaky -> Xh/Xl
      float bc[4];
#pragma unroll
      for (int n = 0; n < 4; ++n) bc[n] = b1[wc * 64 + n * 16 + lo];
#pragma unroll
      for (int m = 0; m < 4; ++m)
#pragma unroll
        for (int j = 0; j < 4; ++j) {
          const int row = m * 16 + 4 * q + j;
#pragma unroll
          for (int n = 0; n < 4; ++n) {
            float v = acc[m][n][j] + bc[n];
            v = v > 0.f ? v : 0.01f * v;
            const int col = wc * 64 + n * 16 + lo;
            const int sidx = row * 256 + ((((col >> 3) ^ (row & 7)) << 3) | (col & 7));
            short h = f2bs(v);
            Xh[sidx] = h;
            Xl[sidx] = f2bs(v - bs2f(h));
          }
        }
    }
    __syncthreads();

    // ===== layers 2 and 3 =====
#pragma unroll 1
    for (int layer = 0; layer < 2; ++layer) {
      const short* Bh = layer ? PW3h : PW2h;
      const short* Bl = layer ? PW3l : PW2l;
      const float* bb = layer ? b3 : b2;
#pragma unroll
      for (int m = 0; m < 4; ++m)
#pragma unroll
        for (int n = 0; n < 4; ++n) acc[m][n] = (f32x4){0.f, 0.f, 0.f, 0.f};
#pragma unroll 2
      for (int ks = 0; ks < 8; ++ks) {
        short8v ah[4], al[4];
#pragma unroll
        for (int m = 0; m < 4; ++m) {
          const int row = m * 16 + lo;
          const int ck = (ks * 4 + q) ^ (row & 7);
          ah[m] = *(const short8v*)&Xh[row * 256 + ck * 8];
          al[m] = *(const short8v*)&Xl[row * 256 + ck * 8];
        }
#pragma unroll
        for (int n = 0; n < 4; ++n) {
          const size_t off = ((size_t)((wc * 4 + n) * 8 + ks) * 64 + lane) * 8;
          short8v bh = *(const short8v*)(Bh + off);
          short8v bl = *(const short8v*)(Bl + off);
#pragma unroll
          for (int m = 0; m < 4; ++m) {
            acc[m][n] = __builtin_amdgcn_mfma_f32_16x16x32_bf16(ah[m], bh, acc[m][n], 0, 0, 0);
            acc[m][n] = __builtin_amdgcn_mfma_f32_16x16x32_bf16(ah[m], bl, acc[m][n], 0, 0, 0);
            acc[m][n] = __builtin_amdgcn_mfma_f32_16x16x32_bf16(al[m], bh, acc[m][n], 0, 0, 0);
          }
        }
      }
      __syncthreads();
      float bc[4];
#pragma unroll
      for (int n = 0; n < 4; ++n) bc[n] = bb[wc * 64 + n * 16 + lo];
      if (layer == 0) {  // epilogue 2: leaky -> Xh/Xl
#pragma unroll
        for (int m = 0; m < 4; ++m)
#pragma unroll
          for (int j = 0; j < 4; ++j) {
            const int row = m * 16 + 4 * q + j;
#pragma unroll
            for (int n = 0; n < 4; ++n) {
              float v = acc[m][n][j] + bc[n];
              v = v > 0.f ? v : 0.01f * v;
              const int col = wc * 64 + n * 16 + lo;
              const int sidx = row * 256 + ((((col >> 3) ^ (row & 7)) << 3) | (col & 7));
              short h = f2bs(v);
              Xh[sidx] = h;
              Xl[sidx] = f2bs(v - bs2f(h));
            }
          }
        __syncthreads();
      } else {  // + b3 into acc
#pragma unroll
        for (int m = 0; m < 4; ++m)
#pragma unroll
          for (int n = 0; n < 4; ++n)
#pragma unroll
            for (int j = 0; j < 4; ++j) acc[m][n][j] += bc[n];
      }
    }

    // ===== argmax =====
#pragma unroll
    for (int m = 0; m < 4; ++m)
#pragma unroll
      for (int j = 0; j < 4; ++j) {
        const int r = m * 16 + 4 * q + j;
        float mx = acc[m][0][j];
        int mi = wc * 64 + lo;
#pragma unroll
        for (int n = 1; n < 4; ++n) {
          float v = acc[m][n][j];
          int c = wc * 64 + n * 16 + lo;
          if (v > mx || (v == mx && c < mi)) { mx = v; mi = c; }
        }
#pragma unroll
        for (int off = 1; off < 16; off <<= 1) {
          float ov = __shfl_xor(mx, off, 64);
          int oi = __shfl_xor(mi, off, 64);
          if (ov > mx || (ov == mx && oi < mi)) { mx = ov; mi = oi; }
        }
        if (lo == 0) { redV[wc][r] = mx; redI[wc][r] = __int_as_float(mi); }
      }
    __syncthreads();
    if (t < BM) {
      float gm = -3.4e38f;
      int gi = 0;
#pragma unroll
      for (int w = 0; w < 4; ++w) {
        float v = redV[w][t];
        int i2 = __float_as_int(redI[w][t]);
        if (v > gm || (v == gm && i2 < gi)) { gm = v; gi = i2; }
      }
      idx_out[rid[t]] = (float)gi;
    }
    __syncthreads();
  }
}

// ---------------- gamma_sum reduce: gsp[3125][256] -> gsum[256] ----------------
__global__ __launch_bounds__(256) void gsum_reduce_kernel(const float* __restrict__ gsp,
                                                          float* __restrict__ gsum) {
  const int b = blockIdx.x;   // 0..24
  const int k = threadIdx.x;
  float s = 0.0f;
  for (int i = 0; i < 125; ++i) s += gsp[(size_t)(b * 125 + i) * KC + k];
  atomicAdd(&gsum[k], s);
}

// ---------------- KL over packed gamma (gammaP) ----------------
__global__ __launch_bounds__(256) void kl_kernel(const short* __restrict__ gP,
                                                 const float* __restrict__ gsum,
                                                 float* __restrict__ out_kl) {
  const int t = threadIdx.x;
  const int w = t >> 6, lane = t & 63;
  const int lo = lane & 15;
  __shared__ float bsum[4];
  float kacc = 0.f;
#pragma unroll 1
  for (int it = 0; it < 2; ++it) {
    const int ns = blockIdx.x * 8 + w * 2 + it;
    if (ns < NSTEPS) {
      float s12[8], m[8], s[8];
#pragma unroll
      for (int j = 0; j < 8; ++j) { s12[j] = 0.f; m[j] = 0.f; s[j] = 0.f; }
#pragma unroll 1
      for (int kf = 0; kf < 16; ++kf) {
        short8v g8 = *(const short8v*)(gP + ((size_t)(ns * 16 + kf) * 64 + lane) * 8);
        const float rg = 1.0f / gsum[kf * 16 + lo];
#pragma unroll
        for (int j = 0; j < 8; ++j) {
          float g = bs2f(g8[j]);
          float y = g * g * rg;
          s12[j] += (g > 0.f ? g * __logf(g) : 0.f) - g * y;
          float nm = fmaxf(m[j], y);
          s[j] = s[j] * __expf(m[j] - nm) + __expf(y - nm);
          m[j] = nm;
        }
      }
#pragma unroll
      for (int off = 1; off < 16; off <<= 1) {
#pragma unroll
        for (int j = 0; j < 8; ++j) {
          float om = __shfl_xor(m[j], off, 64);
          float os = __shfl_xor(s[j], off, 64);
          float nm = fmaxf(m[j], om);
          s[j] = s[j] * __expf(m[j] - nm) + os * __expf(om - nm);
          m[j] = nm;
          s12[j] += __shfl_xor(s12[j], off, 64);
        }
      }
      if (lo == 0) {
#pragma unroll
        for (int j = 0; j < 8; ++j) kacc += s12[j] + m[j] + __logf(s[j]);
      }
    }
  }
#pragma unroll
  for (int off = 1; off < 64; off <<= 1) kacc += __shfl_xor(kacc, off, 64);
  if (lane == 0) bsum[w] = kacc;
  __syncthreads();
  if (t == 0) atomicAdd(out_kl, bsum[0] + bsum[1] + bsum[2] + bsum[3]);
}

// ---------------- mean GEMM: partial[c] += gammaP^T-block @ EP-block (MFMA) -----------
__global__ __launch_bounds__(256, 4) void mean_mfma(const short* __restrict__ gP,
                                                    const short* __restrict__ EP,
                                                    float* __restrict__ partial) {
  const int t = threadIdx.x;
  const int w = t >> 6, lane = t & 63;
  const int kt = blockIdx.x >> 1;
  const int dt = blockIdx.x & 1;
  const int c = blockIdx.y;
  f32x4 acc[4][4];
#pragma unroll
  for (int i = 0; i < 4; ++i)
#pragma unroll
    for (int j = 0; j < 4; ++j) acc[i][j] = (f32x4){0.f, 0.f, 0.f, 0.f};

  const int ns0 = c * MSTEPS;
#pragma unroll 2
  for (int nsi = 0; nsi < MSTEPS; ++nsi) {
    const int ns = ns0 + nsi;
    short8v af[4], bf[4];
#pragma unroll
    for (int i = 0; i < 4; ++i)
      af[i] = *(const short8v*)(gP + ((size_t)(ns * 16 + kt * 4 + i) * 64 + lane) * 8);
#pragma unroll
    for (int j = 0; j < 4; ++j)
      bf[j] = *(const short8v*)(EP + ((size_t)(ns * 32 + dt * 16 + w * 4 + j) * 64 + lane) * 8);
#pragma unroll
    for (int i = 0; i < 4; ++i)
#pragma unroll
      for (int j = 0; j < 4; ++j)
        acc[i][j] = __builtin_amdgcn_mfma_f32_16x16x32_bf16(af[i], bf[j], acc[i][j], 0, 0, 0);
  }
  const int lo = lane & 15, q = lane >> 4;
  const size_t pbase = (size_t)c * (KC * DIM);
#pragma unroll
  for (int i = 0; i < 4; ++i)
#pragma unroll
    for (int j = 0; j < 4; ++j) {
      const int d = dt * 256 + w * 64 + j * 16 + lo;
#pragma unroll
      for (int r = 0; r < 4; ++r) {
        const int k = kt * 64 + i * 16 + q * 4 + r;
        partial[pbase + (size_t)k * DIM + d] = acc[i][j][r];
      }
    }
}

// ---------------- mean pass 2: reduce chunks, divide by gamma_sum ----------------
__global__ __launch_bounds__(256) void mean_pass2(const float* __restrict__ partial,
                                                  const float* __restrict__ gsum,
                                                  float* __restrict__ out_mean) {
  const int t = blockIdx.x * 256 + threadIdx.x;
  float s = 0.0f;
  for (int c = 0; c < MCHUNKS; ++c) s += partial[(size_t)c * (KC * DIM) + t];
  out_mean[t] = s / gsum[t >> 9];
}

extern "C" void kernel_launch(void* const* d_in, const int* in_sizes, int n_in,
                              void* d_out, int out_size, void* d_ws, size_t ws_size,
                              hipStream_t stream) {
  const float* E  = (const float*)d_in[0];
  const float* W1 = (const float*)d_in[1];
  const float* b1 = (const float*)d_in[2];
  const float* W2 = (const float*)d_in[3];
  const float* b2 = (const float*)d_in[4];
  const float* W3 = (const float*)d_in[5];
  const float* b3 = (const float*)d_in[6];
  float* out = (float*)d_out;  // [0]=kl, [1..N]=indices(float), [1+N..]=mean[K][D]

  char* p = (char*)d_ws;
  short* gammaP = (short*)p; p += (size_t)NROWS * KC * 2;            // 102.4 MB
  short* EPb    = (short*)p; p += (size_t)NROWS * DIM * 2;           // 204.8 MB
  float* gsp    = (float*)p; p += (size_t)NBLK_MLP * KC * 4;         // 3.2 MB
  float* gsum   = (float*)p; p += KC * 4;
  short* pw1h   = (short*)p; p += (size_t)KC * DIM * 2;
  short* pw1l   = (short*)p; p += (size_t)KC * DIM * 2;
  short* pw2h   = (short*)p; p += (size_t)KC * KC * 2;
  short* pw2l   = (short*)p; p += (size_t)KC * KC * 2;
  short* pw3h   = (short*)p; p += (size_t)KC * KC * 2;
  short* pw3l   = (short*)p; p += (size_t)KC * KC * 2;
  int* tcnt     = (int*)p;   p += 256;
  int* tlist    = (int*)p;   p += (size_t)NROWS * 4;                 // 0.8 MB
  float* mpart  = (float*)p; p += (size_t)MCHUNKS * KC * DIM * 4;    // 67.1 MB

  hipMemsetAsync(d_out, 0, sizeof(float), stream);
  hipMemsetAsync(gsum, 0, KC * sizeof(float), stream);
  hipMemsetAsync(tcnt, 0, sizeof(int), stream);

  packW_kernel<<<64, 256, 0, stream>>>(W1, pw1h, pw1l, DIM);
  packW_kernel<<<32, 256, 0, stream>>>(W2, pw2h, pw2l, KC);
  packW_kernel<<<32, 256, 0, stream>>>(W3, pw3h, pw3l, KC);
  packE_kernel<<<50000, 256, 0, stream>>>(E, EPb);

  mlp_mfma_kernel<<<NBLK_MLP, 256, 0, stream>>>(E, pw1h, pw2h, pw3h, b1, b2, b3,
                                                gammaP, out + 1, gsp, tcnt, tlist);
  recompute_mfma_kernel<<<512, 256, 0, stream>>>(E, pw1h, pw1l, pw2h, pw2l, pw3h, pw3l,
                                                 b1, b2, b3, tcnt, tlist, out + 1);
  gsum_reduce_kernel<<<25, 256, 0, stream>>>(gsp, gsum);
  kl_kernel<<<(NSTEPS + 7) / 8, 256, 0, stream>>>(gammaP, gsum, out);
  mean_mfma<<<dim3(8, MCHUNKS), 256, 0, stream>>>(gammaP, EPb, mpart);
  mean_pass2<<<(KC * DIM) / 256, 256, 0, stream>>>(mpart, gsum, out + 1 + NROWS);
}